// Round 8
// baseline (1814.320 us; speedup 1.0000x reference)
//
#include <hip/hip_runtime.h>
#include <cstdint>
#include <cstddef>

// ---------------------------------------------------------------------------
// ActorNetSpiking: layer-by-layer over time; spike trains bit-packed (L2-
// resident); FC layers as exact-order f32 GEMM: A-bits in VGPRs (expand
// in-reg), B triple-buffered in LDS via global_load_lds with counted vmcnt
// and raw s_barrier (loads stay in flight across the barrier). Per-output
// arithmetic: k-ascending single-accumulator IEEE-FMA chain + bias-last --
// bit-identical to the validated round-0/4/5/7 numerics.
// ---------------------------------------------------------------------------

#define NB 4096
#define MTOT (NB * 50)

__device__ __forceinline__ void neuron_update(float syn, float& u, float& v, float& s) {
    u = u * 0.5f + syn;
    v = v * 0.75f * (1.0f - s) + u;
    s = (v > 0.5f) ? 1.0f : 0.0f;
}

// ------------------------- conv1: (B,1,360) -> (B,5,178) --------------------
__global__ __launch_bounds__(192) void conv1_kernel(
    const float* __restrict__ x, const float* __restrict__ w1,
    const float* __restrict__ b1, unsigned long long* __restrict__ S1)
{
    __shared__ float xl[9000];
    const int tid = threadIdx.x;
    const int b = blockIdx.x;
    const int j = tid;
    const int lbase = (j < 178) ? 2 * j : 354;

    float wr[25], br[5];
#pragma unroll
    for (int q = 0; q < 25; ++q) wr[q] = w1[q];
#pragma unroll
    for (int o = 0; o < 5; ++o) br[o] = b1[o];

    float u[5], v[5], s[5];
#pragma unroll
    for (int o = 0; o < 5; ++o) { u[o] = 0.f; v[o] = 0.f; s[o] = 0.f; }

    const float* xb = x + (size_t)b * 18000;
    for (int half = 0; half < 2; ++half) {
        const int t0 = half * 25;
        __syncthreads();
        for (int e = tid; e < 9000; e += 192)
            xl[e] = xb[(e / 25) * 50 + t0 + (e % 25)];
        __syncthreads();
        for (int dt = 0; dt < 25; ++dt) {
            const int t = t0 + dt;
            float xv[5];
#pragma unroll
            for (int k = 0; k < 5; ++k) xv[k] = xl[(lbase + k) * 25 + dt];
#pragma unroll
            for (int o = 0; o < 5; ++o) {
                float syn = 0.f;
#pragma unroll
                for (int k = 0; k < 5; ++k) syn += wr[o * 5 + k] * xv[k];
                syn += br[o];
                neuron_update(syn, u[o], v[o], s[o]);
                unsigned long long m = __ballot(j < 178 && s[o] > 0.5f);
                if ((tid & 63) == 0)
                    S1[(((size_t)b * 50 + t) * 5 + o) * 3 + (tid >> 6)] = m;
            }
        }
    }
}

// ------------------------- conv2: (B,5,178) -> (B,5,87) ---------------------
__global__ __launch_bounds__(128) void conv2_kernel(
    const unsigned int* __restrict__ S1, const float* __restrict__ w2,
    const float* __restrict__ b2, unsigned int* __restrict__ S2)
{
    __shared__ unsigned int s1l[1501];
    const int tid = threadIdx.x;
    const int b = blockIdx.x;

    float wr[125], br[5];
#pragma unroll
    for (int q = 0; q < 125; ++q) wr[q] = w2[q];
#pragma unroll
    for (int o = 0; o < 5; ++o) br[o] = b2[o];

    const unsigned int* src = S1 + (size_t)b * 1500;
    for (int e = tid; e < 1500; e += 128) s1l[e] = src[e];
    __syncthreads();

    const int p = (tid < 87) ? 2 * tid : 172;
    const int pw = p >> 5, ps = p & 31;

    float u[5], v[5], s[5];
#pragma unroll
    for (int o = 0; o < 5; ++o) { u[o] = 0.f; v[o] = 0.f; s[o] = 0.f; }

    for (int t = 0; t < 50; ++t) {
        float xv[25];
#pragma unroll
        for (int ci = 0; ci < 5; ++ci) {
            const int base = (t * 5 + ci) * 6 + pw;
            unsigned long long bits =
                ((((unsigned long long)s1l[base + 1]) << 32) | (unsigned long long)s1l[base]) >> ps;
#pragma unroll
            for (int k = 0; k < 5; ++k)
                xv[ci * 5 + k] = ((bits >> k) & 1ULL) ? 1.0f : 0.0f;
        }
#pragma unroll
        for (int o = 0; o < 5; ++o) {
            float syn = 0.f;
#pragma unroll
            for (int q = 0; q < 25; ++q) syn += wr[o * 25 + q] * xv[q];
            syn += br[o];
            neuron_update(syn, u[o], v[o], s[o]);
            unsigned long long m = __ballot(tid < 87 && s[o] > 0.5f);
            const size_t outb = (((size_t)b * 50 + t) * 5 + o) * 3;
            if (tid == 0) {
                S2[outb]     = (unsigned int)m;
                S2[outb + 1] = (unsigned int)(m >> 32);
            }
            if (tid == 64) S2[outb + 2] = (unsigned int)m;
        }
    }
}

// ------------------------- conv3: (B,5,87) -> transposed 216-bit rows -------
__global__ __launch_bounds__(64) void conv3_kernel(
    const unsigned int* __restrict__ S2, const float* __restrict__ w3,
    const float* __restrict__ b3, const float* __restrict__ normal,
    unsigned int* __restrict__ ST0)
{
    __shared__ unsigned int s2l[751];
    const int tid = threadIdx.x;
    const int b = blockIdx.x;

    float wr[125], br[5];
#pragma unroll
    for (int q = 0; q < 125; ++q) wr[q] = w3[q];
#pragma unroll
    for (int o = 0; o < 5; ++o) br[o] = b3[o];

    const unsigned int* src = S2 + (size_t)b * 750;
    for (int e = tid; e < 750; e += 64) s2l[e] = src[e];
    __syncthreads();

    const int p = (tid < 42) ? 2 * tid : 82;
    const int pw = p >> 5, ps = p & 31;

    float u[5], v[5], s[5];
#pragma unroll
    for (int o = 0; o < 5; ++o) { u[o] = 0.f; v[o] = 0.f; s[o] = 0.f; }

    for (int t = 0; t < 50; ++t) {
        float xv[25];
#pragma unroll
        for (int ci = 0; ci < 5; ++ci) {
            const int base = (t * 5 + ci) * 3 + pw;
            unsigned long long bits =
                ((((unsigned long long)s2l[base + 1]) << 32) | (unsigned long long)s2l[base]) >> ps;
#pragma unroll
            for (int k = 0; k < 5; ++k)
                xv[ci * 5 + k] = ((bits >> k) & 1ULL) ? 1.0f : 0.0f;
        }
        unsigned long long m[5];
#pragma unroll
        for (int o = 0; o < 5; ++o) {
            float syn = 0.f;
#pragma unroll
            for (int q = 0; q < 25; ++q) syn += wr[o * 25 + q] * xv[q];
            syn += br[o];
            neuron_update(syn, u[o], v[o], s[o]);
            m[o] = __ballot(tid < 42 && s[o] > 0.5f);
        }
        const unsigned long long nm =
            __ballot(tid < 6 && normal[((size_t)b * 6 + tid) * 50 + t] > 0.5f);
        if (tid == 0) {
            const unsigned long long r0 = m[0] | (m[1] << 42);
            const unsigned long long r1 = (m[1] >> 22) | (m[2] << 20) | (m[3] << 62);
            const unsigned long long r2 = (m[3] >> 2) | (m[4] << 40);
            const unsigned long long r3 = (m[4] >> 24) | (nm << 18);
            const size_t mrow = (size_t)b * 50 + t;
            ST0[0 * (size_t)MTOT + mrow] = (unsigned int)r0;
            ST0[1 * (size_t)MTOT + mrow] = (unsigned int)(r0 >> 32);
            ST0[2 * (size_t)MTOT + mrow] = (unsigned int)r1;
            ST0[3 * (size_t)MTOT + mrow] = (unsigned int)(r1 >> 32);
            ST0[4 * (size_t)MTOT + mrow] = (unsigned int)r2;
            ST0[5 * (size_t)MTOT + mrow] = (unsigned int)(r2 >> 32);
            ST0[6 * (size_t)MTOT + mrow] = (unsigned int)r3;
        }
    }
}

// ------------------------- weight transpose prep ----------------------------
__global__ __launch_bounds__(256) void transpose_w_kernel(
    const float* __restrict__ W, float* __restrict__ Wt, int N, int KREAL, int KPAD)
{
    const int idx = blockIdx.x * 256 + threadIdx.x;
    if (idx >= KPAD * N) return;
    const int k = idx / N, n = idx % N;
    Wt[idx] = (k < KREAL) ? W[(size_t)n * KREAL + k] : 0.f;
}

// ------------------------- fma GEMM: A-bits in VGPR, B in LDS (3-buf) -------
// Tile 128m x 128n, 256 threads; thread = 8m (tm=tid&15) x 8n (tn=tid>>4).
// Pipeline: vmcnt(4) + raw s_barrier, THEN issue loadA(kt+1)/stage(kt+2),
// then compute(kt). 3 LDS buffers make one barrier per iter sufficient.
template <int NTOT, int KT>
__global__ __launch_bounds__(256, 4) void fma_gemm_kernel(
    const uint32_t* __restrict__ bitsT,   // [>=KT][MTOT] u32 planes
    const float* __restrict__ Wt,         // [KT*32][NTOT]
    const float* __restrict__ bias,       // (NTOT,)
    float* __restrict__ syn,              // [Mchunk][NTOT]
    int row0)
{
    __shared__ __align__(16) float blds[3][32 * 128];   // 3 x 16KB

    const int tid = threadIdx.x;
    const int lane = tid & 63;
    const int wid = tid >> 6;
    const int tm = tid & 15;
    const int tn = tid >> 4;
    const int m0 = blockIdx.x * 128;
    const int nbase = blockIdx.y * 128;

    // B staging: [32 k][128 n] f32 = 16KB per buffer, 4 x global_load_lds(16B)
    auto stage = [&](int kt, int buf) {
#pragma unroll
        for (int j = 0; j < 4; ++j) {
            const int c = (j * 4 + wid) * 64 + lane;        // 16B chunk id
            const int row = c >> 5, col = c & 31;
            const float* src = Wt + (size_t)(kt * 32 + row) * NTOT + nbase + col * 4;
            float* dst = &blds[buf][0] + (size_t)(j * 4 + wid) * 256 + lane * 4;
            __builtin_amdgcn_global_load_lds(
                (const __attribute__((address_space(1))) uint32_t*)src,
                (__attribute__((address_space(3))) uint32_t*)dst, 16, 0, 0);
        }
    };

    const int rowA = row0 + m0 + tm * 8;
    auto loadA = [&](int kt, uint4& q0, uint4& q1) {
        const uint32_t* p = bitsT + (size_t)kt * MTOT + rowA;
        q0 = *reinterpret_cast<const uint4*>(p);
        q1 = *reinterpret_cast<const uint4*>(p + 4);
    };

    // prologue: loadA first, then stages (issue order matters for vmcnt count)
    uint4 A0, A1, N0, N1;
    loadA(0, A0, A1);
    stage(0, 0);
    stage(1, 1);

    float acc[8][8];
#pragma unroll
    for (int mi = 0; mi < 8; ++mi)
#pragma unroll
        for (int r = 0; r < 8; ++r) acc[mi][r] = 0.f;

#pragma unroll 1
    for (int kt = 0; kt < KT; ++kt) {
        // wait for loadA(kt) + stage(kt); leave newest stage in flight
        if (kt == KT - 1) asm volatile("s_waitcnt vmcnt(0)\ns_barrier" ::: "memory");
        else              asm volatile("s_waitcnt vmcnt(4)\ns_barrier" ::: "memory");

        // issue next loads AFTER the barrier (prev readers of target buf done)
        if (kt + 1 < KT) loadA(kt + 1, N0, N1);
        if (kt + 2 < KT) stage(kt + 2, (kt + 2) % 3);

        const uint32_t awv[8] = {A0.x, A0.y, A0.z, A0.w, A1.x, A1.y, A1.z, A1.w};
        const float* bt = &blds[kt % 3][0];

#pragma unroll
        for (int kk = 0; kk < 32; ++kk) {
            const float4 b0 = *reinterpret_cast<const float4*>(bt + kk * 128 + tn * 8);
            const float4 b1 = *reinterpret_cast<const float4*>(bt + kk * 128 + tn * 8 + 4);
#pragma unroll
            for (int mi = 0; mi < 8; ++mi) {
                const float a = (float)((awv[mi] >> kk) & 1u);
                acc[mi][0] = fmaf(a, b0.x, acc[mi][0]);
                acc[mi][1] = fmaf(a, b0.y, acc[mi][1]);
                acc[mi][2] = fmaf(a, b0.z, acc[mi][2]);
                acc[mi][3] = fmaf(a, b0.w, acc[mi][3]);
                acc[mi][4] = fmaf(a, b1.x, acc[mi][4]);
                acc[mi][5] = fmaf(a, b1.y, acc[mi][5]);
                acc[mi][6] = fmaf(a, b1.z, acc[mi][6]);
                acc[mi][7] = fmaf(a, b1.w, acc[mi][7]);
            }
        }
        A0 = N0; A1 = N1;
    }

    // epilogue: bias-last, coalesced float4 stores
    const int nb = nbase + tn * 8;
    float bsv[8];
#pragma unroll
    for (int q = 0; q < 8; ++q) bsv[q] = bias[nb + q];
#pragma unroll
    for (int mi = 0; mi < 8; ++mi) {
        float* so = syn + (size_t)(m0 + tm * 8 + mi) * NTOT + nb;
        float4 o0, o1;
        o0.x = acc[mi][0] + bsv[0]; o0.y = acc[mi][1] + bsv[1];
        o0.z = acc[mi][2] + bsv[2]; o0.w = acc[mi][3] + bsv[3];
        o1.x = acc[mi][4] + bsv[4]; o1.y = acc[mi][5] + bsv[5];
        o1.z = acc[mi][6] + bsv[6]; o1.w = acc[mi][7] + bsv[7];
        *reinterpret_cast<float4*>(so) = o0;
        *reinterpret_cast<float4*>(so + 4) = o1;
    }
}

// ------------------------- FC scan (N=256): LIF -> transposed bit planes ----
__global__ __launch_bounds__(256) void fc_scanT_kernel(
    const float* __restrict__ syn, uint32_t* __restrict__ SFT, int b0)
{
    const int tid = threadIdx.x;
    const int lane = tid & 63;
    const int ob = tid >> 6;
    const int bl = blockIdx.x;
    const int o = ob * 64 + lane;

    float u = 0.f, v = 0.f, s = 0.f;
    for (int t = 0; t < 50; ++t) {
        const float sv = syn[((size_t)bl * 50 + t) * 256 + o];
        neuron_update(sv, u, v, s);
        const unsigned long long m = __ballot(s > 0.5f);
        if (lane == 0) {
            const size_t row = (size_t)(b0 + bl) * 50 + t;
            SFT[(size_t)(2 * ob) * MTOT + row]     = (uint32_t)m;
            SFT[(size_t)(2 * ob + 1) * MTOT + row] = (uint32_t)(m >> 32);
        }
    }
}

// ------------------------- FC scan (N=128): LIF -> u64 rows -----------------
__global__ __launch_bounds__(256) void fc_scan128_kernel(
    const float* __restrict__ syn, unsigned long long* __restrict__ SF, int b0)
{
    const int tid = threadIdx.x;
    const int wid = blockIdx.x * 4 + (tid >> 6);
    const int lane = tid & 63;
    const int bl = wid >> 1;
    const int ob = wid & 1;
    const int o = ob * 64 + lane;

    float u = 0.f, v = 0.f, s = 0.f;
    for (int t = 0; t < 50; ++t) {
        const float sv = syn[((size_t)bl * 50 + t) * 128 + o];
        neuron_update(sv, u, v, s);
        const unsigned long long m = __ballot(s > 0.5f);
        if (lane == 0) SF[((size_t)(b0 + bl) * 50 + t) * 2 + ob] = m;
    }
}

// ------------------------- fc4 GEMM (N=2, K=128) ----------------------------
__global__ __launch_bounds__(256) void fc4_gemm_kernel(
    const unsigned long long* __restrict__ SF3, const float* __restrict__ W,
    const float* __restrict__ bias, float* __restrict__ syn4)
{
    const int m = blockIdx.x * 256 + threadIdx.x;
    const unsigned long long w0 = SF3[(size_t)m * 2];
    const unsigned long long w1 = SF3[(size_t)m * 2 + 1];
    float a0 = 0.f, a1 = 0.f;
#pragma unroll
    for (int i = 0; i < 64; ++i) {
        const float bit = ((w0 >> i) & 1ULL) ? 1.f : 0.f;
        a0 = fmaf(bit, W[i], a0);
        a1 = fmaf(bit, W[128 + i], a1);
    }
#pragma unroll
    for (int i = 0; i < 64; ++i) {
        const float bit = ((w1 >> i) & 1ULL) ? 1.f : 0.f;
        a0 = fmaf(bit, W[64 + i], a0);
        a1 = fmaf(bit, W[192 + i], a1);
    }
    syn4[(size_t)m * 2]     = a0 + bias[0];
    syn4[(size_t)m * 2 + 1] = a1 + bias[1];
}

__global__ __launch_bounds__(64) void fc4_scan_kernel(
    const float* __restrict__ syn4, float* __restrict__ out)
{
    const int b = blockIdx.x * 64 + threadIdx.x;
    float u0 = 0.f, v0 = 0.f, s0 = 0.f, acc0 = 0.f;
    float u1 = 0.f, v1 = 0.f, s1 = 0.f, acc1 = 0.f;
    for (int t = 0; t < 50; ++t) {
        const float x0 = syn4[((size_t)b * 50 + t) * 2];
        const float x1 = syn4[((size_t)b * 50 + t) * 2 + 1];
        neuron_update(x0, u0, v0, s0); acc0 += s0;
        neuron_update(x1, u1, v1, s1); acc1 += s1;
    }
    out[b * 2]     = acc0 / 50.0f;
    out[b * 2 + 1] = acc1 / 50.0f;
}

// ---------------------------------------------------------------------------
extern "C" void kernel_launch(void* const* d_in, const int* in_sizes, int n_in,
                              void* d_out, int out_size, void* d_ws, size_t ws_size,
                              hipStream_t stream) {
    (void)in_sizes; (void)n_in; (void)out_size;
    const float* normal = (const float*)d_in[0];
    const float* xscan  = (const float*)d_in[1];
    const float* w1  = (const float*)d_in[3];
    const float* b1  = (const float*)d_in[4];
    const float* w2  = (const float*)d_in[5];
    const float* b2  = (const float*)d_in[6];
    const float* w3  = (const float*)d_in[7];
    const float* b3  = (const float*)d_in[8];
    const float* fw1 = (const float*)d_in[9];
    const float* fb1 = (const float*)d_in[10];
    const float* fw2 = (const float*)d_in[11];
    const float* fb2 = (const float*)d_in[12];
    const float* fw3 = (const float*)d_in[13];
    const float* fb3 = (const float*)d_in[14];
    const float* fw4 = (const float*)d_in[15];
    const float* fb4 = (const float*)d_in[16];
    float* out = (float*)d_out;

    char* wp = (char*)d_ws;
    size_t off = 0;
    auto take = [&](size_t bytes) -> void* {
        void* p = wp + off;
        off += (bytes + 255) & ~(size_t)255;
        return p;
    };
    float* Wt1 = (float*)take((size_t)224 * 256 * 4);
    float* Wt2 = (float*)take((size_t)256 * 256 * 4);
    float* Wt3 = (float*)take((size_t)256 * 128 * 4);
    unsigned long long* S1  = (unsigned long long*)take((size_t)NB * 50 * 15 * 8);
    unsigned int*       S2  = (unsigned int*)take((size_t)NB * 50 * 15 * 4);
    uint32_t* ST0 = (uint32_t*)take((size_t)8 * MTOT * 4);
    uint32_t* ST1 = (uint32_t*)take((size_t)8 * MTOT * 4);
    uint32_t* ST2 = (uint32_t*)take((size_t)8 * MTOT * 4);
    unsigned long long* SF3 = (unsigned long long*)take((size_t)MTOT * 2 * 8);
    float*              syn4 = (float*)take((size_t)MTOT * 2 * 4);

    int chunk = NB;
    while (chunk > 128 && off + (size_t)chunk * 50 * 256 * 4 > ws_size) chunk >>= 1;
    float* syn = (float*)take((size_t)chunk * 50 * 256 * 4);

    transpose_w_kernel<<<(224 * 256 + 255) / 256, 256, 0, stream>>>(fw1, Wt1, 256, 216, 224);
    transpose_w_kernel<<<(256 * 256 + 255) / 256, 256, 0, stream>>>(fw2, Wt2, 256, 256, 256);
    transpose_w_kernel<<<(256 * 128 + 255) / 256, 256, 0, stream>>>(fw3, Wt3, 128, 256, 256);

    conv1_kernel<<<NB, 192, 0, stream>>>(xscan, w1, b1, S1);
    conv2_kernel<<<NB, 128, 0, stream>>>((const unsigned int*)S1, w2, b2, S2);
    conv3_kernel<<<NB, 64, 0, stream>>>(S2, w3, b3, normal, ST0);

    for (int b0 = 0; b0 < NB; b0 += chunk) {
        fma_gemm_kernel<256, 7><<<dim3(chunk * 50 / 128, 2), 256, 0, stream>>>(
            ST0, Wt1, fb1, syn, b0 * 50);
        fc_scanT_kernel<<<chunk, 256, 0, stream>>>(syn, ST1, b0);

        fma_gemm_kernel<256, 8><<<dim3(chunk * 50 / 128, 2), 256, 0, stream>>>(
            ST1, Wt2, fb2, syn, b0 * 50);
        fc_scanT_kernel<<<chunk, 256, 0, stream>>>(syn, ST2, b0);

        fma_gemm_kernel<128, 8><<<dim3(chunk * 50 / 128, 1), 256, 0, stream>>>(
            ST2, Wt3, fb3, syn, b0 * 50);
        fc_scan128_kernel<<<chunk / 2, 256, 0, stream>>>(syn, SF3, b0);
    }

    fc4_gemm_kernel<<<MTOT / 256, 256, 0, stream>>>(SF3, fw4, fb4, syn4);
    fc4_scan_kernel<<<NB / 64, 64, 0, stream>>>(syn4, out);
}

// Round 9
// 1781.777 us; speedup vs baseline: 1.0183x; 1.0183x over previous
//
#include <hip/hip_runtime.h>
#include <cstdint>
#include <cstddef>

// ---------------------------------------------------------------------------
// ActorNetSpiking: layer-by-layer over time; spikes bit-packed in transposed
// u32 planes. FC layers: bf16x3-split MFMA GEMM (fast, provisional) + LIF
// scan that FLAGS neurons with any |v-0.5| < DELTA + exact-repair kernel
// (ascending-k single-accumulator f32 fmaf chain, the validated reference
// order) that fixes any provisional spike bits. Output is bit-exact.
// ---------------------------------------------------------------------------

#define NB 4096
#define MTOT (NB * 50)
#define DELTA 1e-3f

typedef __attribute__((ext_vector_type(8))) short bf16x8;
typedef __attribute__((ext_vector_type(4))) float f32x4;
typedef __attribute__((ext_vector_type(4))) uint32_t u32x4;

__device__ __forceinline__ void neuron_update(float syn, float& u, float& v, float& s) {
    u = u * 0.5f + syn;
    v = v * 0.75f * (1.0f - s) + u;
    s = (v > 0.5f) ? 1.0f : 0.0f;
}

// ------------------------- conv1: (B,1,360) -> (B,5,178) --------------------
__global__ __launch_bounds__(192) void conv1_kernel(
    const float* __restrict__ x, const float* __restrict__ w1,
    const float* __restrict__ b1, unsigned long long* __restrict__ S1)
{
    __shared__ float xl[9000];
    const int tid = threadIdx.x;
    const int b = blockIdx.x;
    const int j = tid;
    const int lbase = (j < 178) ? 2 * j : 354;

    float wr[25], br[5];
#pragma unroll
    for (int q = 0; q < 25; ++q) wr[q] = w1[q];
#pragma unroll
    for (int o = 0; o < 5; ++o) br[o] = b1[o];

    float u[5], v[5], s[5];
#pragma unroll
    for (int o = 0; o < 5; ++o) { u[o] = 0.f; v[o] = 0.f; s[o] = 0.f; }

    const float* xb = x + (size_t)b * 18000;
    for (int half = 0; half < 2; ++half) {
        const int t0 = half * 25;
        __syncthreads();
        for (int e = tid; e < 9000; e += 192)
            xl[e] = xb[(e / 25) * 50 + t0 + (e % 25)];
        __syncthreads();
        for (int dt = 0; dt < 25; ++dt) {
            const int t = t0 + dt;
            float xv[5];
#pragma unroll
            for (int k = 0; k < 5; ++k) xv[k] = xl[(lbase + k) * 25 + dt];
#pragma unroll
            for (int o = 0; o < 5; ++o) {
                float syn = 0.f;
#pragma unroll
                for (int k = 0; k < 5; ++k) syn += wr[o * 5 + k] * xv[k];
                syn += br[o];
                neuron_update(syn, u[o], v[o], s[o]);
                unsigned long long m = __ballot(j < 178 && s[o] > 0.5f);
                if ((tid & 63) == 0)
                    S1[(((size_t)b * 50 + t) * 5 + o) * 3 + (tid >> 6)] = m;
            }
        }
    }
}

// ------------------------- conv2: (B,5,178) -> (B,5,87) ---------------------
__global__ __launch_bounds__(128) void conv2_kernel(
    const unsigned int* __restrict__ S1, const float* __restrict__ w2,
    const float* __restrict__ b2, unsigned int* __restrict__ S2)
{
    __shared__ unsigned int s1l[1501];
    const int tid = threadIdx.x;
    const int b = blockIdx.x;

    float wr[125], br[5];
#pragma unroll
    for (int q = 0; q < 125; ++q) wr[q] = w2[q];
#pragma unroll
    for (int o = 0; o < 5; ++o) br[o] = b2[o];

    const unsigned int* src = S1 + (size_t)b * 1500;
    for (int e = tid; e < 1500; e += 128) s1l[e] = src[e];
    __syncthreads();

    const int p = (tid < 87) ? 2 * tid : 172;
    const int pw = p >> 5, ps = p & 31;

    float u[5], v[5], s[5];
#pragma unroll
    for (int o = 0; o < 5; ++o) { u[o] = 0.f; v[o] = 0.f; s[o] = 0.f; }

    for (int t = 0; t < 50; ++t) {
        float xv[25];
#pragma unroll
        for (int ci = 0; ci < 5; ++ci) {
            const int base = (t * 5 + ci) * 6 + pw;
            unsigned long long bits =
                ((((unsigned long long)s1l[base + 1]) << 32) | (unsigned long long)s1l[base]) >> ps;
#pragma unroll
            for (int k = 0; k < 5; ++k)
                xv[ci * 5 + k] = ((bits >> k) & 1ULL) ? 1.0f : 0.0f;
        }
#pragma unroll
        for (int o = 0; o < 5; ++o) {
            float syn = 0.f;
#pragma unroll
            for (int q = 0; q < 25; ++q) syn += wr[o * 25 + q] * xv[q];
            syn += br[o];
            neuron_update(syn, u[o], v[o], s[o]);
            unsigned long long m = __ballot(tid < 87 && s[o] > 0.5f);
            const size_t outb = (((size_t)b * 50 + t) * 5 + o) * 3;
            if (tid == 0) {
                S2[outb]     = (unsigned int)m;
                S2[outb + 1] = (unsigned int)(m >> 32);
            }
            if (tid == 64) S2[outb + 2] = (unsigned int)m;
        }
    }
}

// ------------------------- conv3: (B,5,87) -> transposed 216-bit rows -------
// Bits k=0..209 conv3 spikes (k=o*42+j), 210..215 normal. Planes 0..6 data,
// plane 7 zero (K padding for the MFMA GEMM).
__global__ __launch_bounds__(64) void conv3_kernel(
    const unsigned int* __restrict__ S2, const float* __restrict__ w3,
    const float* __restrict__ b3, const float* __restrict__ normal,
    unsigned int* __restrict__ ST0)
{
    __shared__ unsigned int s2l[751];
    const int tid = threadIdx.x;
    const int b = blockIdx.x;

    float wr[125], br[5];
#pragma unroll
    for (int q = 0; q < 125; ++q) wr[q] = w3[q];
#pragma unroll
    for (int o = 0; o < 5; ++o) br[o] = b3[o];

    const unsigned int* src = S2 + (size_t)b * 750;
    for (int e = tid; e < 750; e += 64) s2l[e] = src[e];
    __syncthreads();

    const int p = (tid < 42) ? 2 * tid : 82;
    const int pw = p >> 5, ps = p & 31;

    float u[5], v[5], s[5];
#pragma unroll
    for (int o = 0; o < 5; ++o) { u[o] = 0.f; v[o] = 0.f; s[o] = 0.f; }

    for (int t = 0; t < 50; ++t) {
        float xv[25];
#pragma unroll
        for (int ci = 0; ci < 5; ++ci) {
            const int base = (t * 5 + ci) * 3 + pw;
            unsigned long long bits =
                ((((unsigned long long)s2l[base + 1]) << 32) | (unsigned long long)s2l[base]) >> ps;
#pragma unroll
            for (int k = 0; k < 5; ++k)
                xv[ci * 5 + k] = ((bits >> k) & 1ULL) ? 1.0f : 0.0f;
        }
        unsigned long long m[5];
#pragma unroll
        for (int o = 0; o < 5; ++o) {
            float syn = 0.f;
#pragma unroll
            for (int q = 0; q < 25; ++q) syn += wr[o * 25 + q] * xv[q];
            syn += br[o];
            neuron_update(syn, u[o], v[o], s[o]);
            m[o] = __ballot(tid < 42 && s[o] > 0.5f);
        }
        const unsigned long long nm =
            __ballot(tid < 6 && normal[((size_t)b * 6 + tid) * 50 + t] > 0.5f);
        if (tid == 0) {
            const unsigned long long r0 = m[0] | (m[1] << 42);
            const unsigned long long r1 = (m[1] >> 22) | (m[2] << 20) | (m[3] << 62);
            const unsigned long long r2 = (m[3] >> 2) | (m[4] << 40);
            const unsigned long long r3 = (m[4] >> 24) | (nm << 18);
            const size_t mrow = (size_t)b * 50 + t;
            ST0[0 * (size_t)MTOT + mrow] = (unsigned int)r0;
            ST0[1 * (size_t)MTOT + mrow] = (unsigned int)(r0 >> 32);
            ST0[2 * (size_t)MTOT + mrow] = (unsigned int)r1;
            ST0[3 * (size_t)MTOT + mrow] = (unsigned int)(r1 >> 32);
            ST0[4 * (size_t)MTOT + mrow] = (unsigned int)r2;
            ST0[5 * (size_t)MTOT + mrow] = (unsigned int)(r2 >> 32);
            ST0[6 * (size_t)MTOT + mrow] = (unsigned int)r3;
            ST0[7 * (size_t)MTOT + mrow] = 0u;
        }
    }
}

// ------------------------- weight split+swizzle prep (validated r2) ---------
// W (N,KREAL) f32 -> 3 exact bf16 planes, K padded to 256, tiles
// [nblk][kc(4)][part(3)][row 128][k 64] with (row&7)<<4 16B XOR swizzle.
__global__ __launch_bounds__(256) void pack_w_kernel(
    const float* __restrict__ W, unsigned short* __restrict__ dst, int KREAL)
{
    const int idx = blockIdx.x * 256 + threadIdx.x;
    const int n = idx >> 8, k = idx & 255;
    const float w = (k < KREAL) ? W[(size_t)n * KREAL + k] : 0.f;
    const uint32_t u0 = __float_as_uint(w);
    const unsigned short h0 = (unsigned short)(u0 >> 16);
    const float p0 = __uint_as_float(u0 & 0xFFFF0000u);
    const float r1 = w - p0;
    const uint32_t u1 = __float_as_uint(r1);
    const unsigned short h1 = (unsigned short)(u1 >> 16);
    const float p1 = __uint_as_float(u1 & 0xFFFF0000u);
    const float r2 = r1 - p1;
    const unsigned short h2 = (unsigned short)(__float_as_uint(r2) >> 16);

    const int nb = n >> 7, row = n & 127;
    const int kc = k >> 6, kl = k & 63;
    const int kbyte = (kl * 2) ^ ((row & 7) << 4);
    const size_t base = ((size_t)nb * 12 + (size_t)kc * 3) * 8192 + row * 64 + (kbyte >> 1);
    dst[base] = h0;
    dst[base + 8192] = h1;
    dst[base + 16384] = h2;
}

// ------------------------- MFMA FC GEMM (validated r2 structure) ------------
// syn[m][n] = sum_k bits[m][k]*W[n][k] + bias[n]. M tile 128, N tile 128,
// 12 k-steps (4 kc x 3 bf16 parts). A-bits staged once to LDS from planes.
__global__ __launch_bounds__(256, 3) void mfma_fc_kernel(
    const uint32_t* __restrict__ bitsT,       // planes [8][MTOT]
    const unsigned short* __restrict__ wg,    // pre-swizzled tiles
    const float* __restrict__ bias,
    float* __restrict__ syn,                  // [Mchunk][Ntot]
    int Ntot, int row0)
{
    __shared__ __align__(16) unsigned short blds[3][8192];  // 3 x 16KB
    __shared__ __align__(16) uint32_t bits_lds[1024];       // [plane w][128 m]

    const int tid = threadIdx.x;
    const int lane = tid & 63;
    const int wid = tid >> 6;
    const int wm = wid >> 1, wn = wid & 1;
    const int m0 = blockIdx.x * 128;
    const int nb = blockIdx.y;
    const int nbase = nb * 128;

    // stage A bits: plane-major [w][128] (4KB). src per lane: 16B of plane tid>>5.
    {
        const uint32_t* g = bitsT + (size_t)(tid >> 5) * MTOT + (row0 + m0) + (tid & 31) * 4;
        uint32_t* l = bits_lds + wid * 256;
        __builtin_amdgcn_global_load_lds(
            (const __attribute__((address_space(1))) uint32_t*)g,
            (__attribute__((address_space(3))) uint32_t*)l, 16, 0, 0);
    }

    auto stage = [&](int t_idx, int buf) {
        const unsigned short* wt = wg + ((size_t)(nb * 12 + t_idx)) * 8192;
#pragma unroll
        for (int j = 0; j < 4; ++j) {
            const char* g = (const char*)wt + j * 4096 + wid * 1024 + lane * 16;
            char* l = (char*)&blds[buf][0] + j * 4096 + wid * 1024;
            __builtin_amdgcn_global_load_lds(
                (const __attribute__((address_space(1))) uint32_t*)g,
                (__attribute__((address_space(3))) uint32_t*)l, 16, 0, 0);
        }
    };

    stage(0, 0);
    stage(1, 1);

    f32x4 acc[4][4];
#pragma unroll
    for (int i = 0; i < 4; ++i)
#pragma unroll
        for (int j = 0; j < 4; ++j) acc[i][j] = (f32x4){0.f, 0.f, 0.f, 0.f};

    union frag { u32x4 u; bf16x8 h; };
    frag afr[4][2];

#pragma unroll
    for (int s = 0; s < 12; ++s) {
        if (s < 11) asm volatile("s_waitcnt vmcnt(4)\ns_barrier" ::: "memory");
        else        asm volatile("s_waitcnt vmcnt(0)\ns_barrier" ::: "memory");
        if (s + 2 < 12) stage(s + 2, (s + 2) % 3);

        const int kc = s / 3;
        if ((s % 3) == 0) {
#pragma unroll
            for (int mi = 0; mi < 4; ++mi) {
                const int row = wm * 64 + mi * 16 + (lane & 15);
#pragma unroll
                for (int kk = 0; kk < 2; ++kk) {
                    const uint32_t wbits = bits_lds[(kc * 2 + kk) * 128 + row];
                    const uint32_t bb = (wbits >> ((lane >> 4) * 8)) & 0xFFu;
                    u32x4 e;
#pragma unroll
                    for (int j = 0; j < 4; ++j) {
                        uint32_t r = ((bb >> (2 * j)) & 1u) ? 0x3F80u : 0u;
                        if ((bb >> (2 * j + 1)) & 1u) r |= 0x3F800000u;
                        e[j] = r;
                    }
                    afr[mi][kk].u = e;
                }
            }
        }

        const char* bt = (const char*)&blds[s % 3][0];
        __builtin_amdgcn_s_setprio(1);
#pragma unroll
        for (int kk = 0; kk < 2; ++kk) {
#pragma unroll
            for (int ni = 0; ni < 4; ++ni) {
                const int r = wn * 64 + ni * 16 + (lane & 15);
                const int kb = kk * 64 + (lane >> 4) * 16;
                const int off = r * 128 + (kb ^ ((r & 7) << 4));
                bf16x8 bfr = *reinterpret_cast<const bf16x8*>(bt + off);
#pragma unroll
                for (int mi = 0; mi < 4; ++mi)
                    acc[mi][ni] = __builtin_amdgcn_mfma_f32_16x16x32_bf16(
                        afr[mi][kk].h, bfr, acc[mi][ni], 0, 0, 0);
            }
        }
        __builtin_amdgcn_s_setprio(0);
    }

    // epilogue: bias + store (D: col = lane&15, row = 4*(lane>>4)+reg)
#pragma unroll
    for (int ni = 0; ni < 4; ++ni) {
        const int n = nbase + wn * 64 + ni * 16 + (lane & 15);
        const float bs = bias[n];
#pragma unroll
        for (int mi = 0; mi < 4; ++mi) {
            const int mr = m0 + wm * 64 + mi * 16 + ((lane >> 4) << 2);
            float* dst = syn + (size_t)mr * Ntot + n;
            f32x4 a = acc[mi][ni];
#pragma unroll
            for (int rr = 0; rr < 4; ++rr) dst[(size_t)rr * Ntot] = a[rr] + bs;
        }
    }
}

// ------------------------- FC scan + flag: LIF -> planes + repair list ------
template <int N>
__global__ __launch_bounds__(N) void fc_scan_flag_kernel(
    const float* __restrict__ syn,        // [chunk*50][N]
    uint32_t* __restrict__ SFT,           // planes [N/32][MTOT]
    int b0,
    uint32_t* __restrict__ list, unsigned int* __restrict__ cnt)
{
    const int tid = threadIdx.x;
    const int lane = tid & 63;
    const int ob = tid >> 6;
    const int bl = blockIdx.x;
    const int o = tid;

    float u = 0.f, v = 0.f, s = 0.f;
    bool flag = false;
    for (int t = 0; t < 50; ++t) {
        const float sv = syn[((size_t)bl * 50 + t) * N + o];
        u = u * 0.5f + sv;
        v = v * 0.75f * (1.0f - s) + u;
        flag |= (fabsf(v - 0.5f) < DELTA);
        s = (v > 0.5f) ? 1.0f : 0.0f;
        const unsigned long long m = __ballot(s > 0.5f);
        if (lane == 0) {
            const size_t row = (size_t)(b0 + bl) * 50 + t;
            SFT[(size_t)(2 * ob) * MTOT + row]     = (uint32_t)m;
            SFT[(size_t)(2 * ob + 1) * MTOT + row] = (uint32_t)(m >> 32);
        }
    }
    // compact flagged (b,o) into the repair list
    const unsigned long long fm = __ballot(flag);
    unsigned int base = 0;
    if (lane == 0 && fm) base = atomicAdd(cnt, (unsigned int)__popcll(fm));
    base = __shfl(base, 0);
    if (flag) {
        const unsigned int off = (unsigned int)__popcll(fm & ((1ULL << lane) - 1ULL));
        list[base + off] = ((unsigned int)(b0 + bl) << 8) | (unsigned int)o;
    }
}

// ------------------------- exact repair: flagged neurons --------------------
// One wave per flagged (b,o): lane=t computes the exact ascending-k f32 fmaf
// chain + bias (reference order), then a broadcast LIF re-scan; any spike bit
// that differs from the provisional plane word is atomically flipped.
template <int KT, int KREAL>
__global__ __launch_bounds__(256) void repair_kernel(
    const uint32_t* __restrict__ planesIn,   // [KT..8][MTOT]
    const float* __restrict__ W,             // (NOUT, KREAL) row-major
    const float* __restrict__ bias,
    uint32_t* __restrict__ planesOut,        // [NOUT/32][MTOT]
    const uint32_t* __restrict__ list,
    const unsigned int* __restrict__ cnt)
{
    const int lane = threadIdx.x & 63;
    const int wid = blockIdx.x * 4 + (threadIdx.x >> 6);
    const int nwaves = gridDim.x * 4;
    const unsigned int n = *cnt;

    for (unsigned int idx = wid; idx < n; idx += nwaves) {
        const uint32_t e = list[idx];
        const int b = __builtin_amdgcn_readfirstlane((int)(e >> 8));
        const int o = __builtin_amdgcn_readfirstlane((int)(e & 255u));
        const int tl = (lane < 50) ? lane : 49;
        const size_t row = (size_t)b * 50 + tl;

        uint32_t wb[KT];
#pragma unroll
        for (int w = 0; w < KT; ++w) wb[w] = planesIn[(size_t)w * MTOT + row];

        const float* wr = W + (size_t)o * KREAL;
        float acc = 0.f;
#pragma unroll
        for (int kt = 0; kt < KT; ++kt) {
#pragma unroll
            for (int kk = 0; kk < 32; ++kk) {
                const int k = kt * 32 + kk;
                if (k < KREAL)
                    acc = fmaf((float)((wb[kt] >> kk) & 1u), wr[k], acc);
            }
        }
        const float syn_t = acc + bias[o];

        // broadcast LIF scan (all lanes track state; lane t keeps its spike)
        float u = 0.f, v = 0.f, s = 0.f, mys = 0.f;
#pragma unroll 1
        for (int t = 0; t < 50; ++t) {
            const float sv = __shfl(syn_t, t);
            u = u * 0.5f + sv;
            v = v * 0.75f * (1.0f - s) + u;
            s = (v > 0.5f) ? 1.0f : 0.0f;
            if (lane == t) mys = s;
        }

        if (lane < 50) {
            uint32_t* wp = planesOut + (size_t)(o >> 5) * MTOT + row;
            const uint32_t bit = 1u << (o & 31);
            const bool prov = (*wp & bit) != 0u;
            const bool ex = (mys > 0.5f);
            if (prov != ex) atomicXor(wp, bit);
        }
    }
}

// ------------------------- fc4 GEMM (N=2, K=128, exact) ---------------------
__global__ __launch_bounds__(256) void fc4_gemm_kernel(
    const uint32_t* __restrict__ P3,          // planes [4][MTOT]
    const float* __restrict__ W, const float* __restrict__ bias,
    float* __restrict__ syn4)
{
    const int m = blockIdx.x * 256 + threadIdx.x;
    const unsigned long long w0 =
        (unsigned long long)P3[m] | ((unsigned long long)P3[(size_t)MTOT + m] << 32);
    const unsigned long long w1 =
        (unsigned long long)P3[2 * (size_t)MTOT + m] |
        ((unsigned long long)P3[3 * (size_t)MTOT + m] << 32);
    float a0 = 0.f, a1 = 0.f;
#pragma unroll
    for (int i = 0; i < 64; ++i) {
        const float bit = ((w0 >> i) & 1ULL) ? 1.f : 0.f;
        a0 = fmaf(bit, W[i], a0);
        a1 = fmaf(bit, W[128 + i], a1);
    }
#pragma unroll
    for (int i = 0; i < 64; ++i) {
        const float bit = ((w1 >> i) & 1ULL) ? 1.f : 0.f;
        a0 = fmaf(bit, W[64 + i], a0);
        a1 = fmaf(bit, W[192 + i], a1);
    }
    syn4[(size_t)m * 2]     = a0 + bias[0];
    syn4[(size_t)m * 2 + 1] = a1 + bias[1];
}

__global__ __launch_bounds__(64) void fc4_scan_kernel(
    const float* __restrict__ syn4, float* __restrict__ out)
{
    const int b = blockIdx.x * 64 + threadIdx.x;
    float u0 = 0.f, v0 = 0.f, s0 = 0.f, acc0 = 0.f;
    float u1 = 0.f, v1 = 0.f, s1 = 0.f, acc1 = 0.f;
    for (int t = 0; t < 50; ++t) {
        const float x0 = syn4[((size_t)b * 50 + t) * 2];
        const float x1 = syn4[((size_t)b * 50 + t) * 2 + 1];
        neuron_update(x0, u0, v0, s0); acc0 += s0;
        neuron_update(x1, u1, v1, s1); acc1 += s1;
    }
    out[b * 2]     = acc0 / 50.0f;
    out[b * 2 + 1] = acc1 / 50.0f;
}

// ---------------------------------------------------------------------------
extern "C" void kernel_launch(void* const* d_in, const int* in_sizes, int n_in,
                              void* d_out, int out_size, void* d_ws, size_t ws_size,
                              hipStream_t stream) {
    (void)in_sizes; (void)n_in; (void)out_size;
    const float* normal = (const float*)d_in[0];
    const float* xscan  = (const float*)d_in[1];
    const float* w1  = (const float*)d_in[3];
    const float* b1  = (const float*)d_in[4];
    const float* w2  = (const float*)d_in[5];
    const float* b2  = (const float*)d_in[6];
    const float* w3  = (const float*)d_in[7];
    const float* b3  = (const float*)d_in[8];
    const float* fw1 = (const float*)d_in[9];
    const float* fb1 = (const float*)d_in[10];
    const float* fw2 = (const float*)d_in[11];
    const float* fb2 = (const float*)d_in[12];
    const float* fw3 = (const float*)d_in[13];
    const float* fb3 = (const float*)d_in[14];
    const float* fw4 = (const float*)d_in[15];
    const float* fb4 = (const float*)d_in[16];
    float* out = (float*)d_out;

    char* wp = (char*)d_ws;
    size_t off = 0;
    auto take = [&](size_t bytes) -> void* {
        void* p = wp + off;
        off += (bytes + 255) & ~(size_t)255;
        return p;
    };
    unsigned short* Wg1 = (unsigned short*)take((size_t)2 * 12 * 8192 * 2);
    unsigned short* Wg2 = (unsigned short*)take((size_t)2 * 12 * 8192 * 2);
    unsigned short* Wg3 = (unsigned short*)take((size_t)1 * 12 * 8192 * 2);
    unsigned long long* S1  = (unsigned long long*)take((size_t)NB * 50 * 15 * 8);
    unsigned int*       S2  = (unsigned int*)take((size_t)NB * 50 * 15 * 4);
    uint32_t* ST0 = (uint32_t*)take((size_t)8 * MTOT * 4);
    uint32_t* ST1 = (uint32_t*)take((size_t)8 * MTOT * 4);
    uint32_t* ST2 = (uint32_t*)take((size_t)8 * MTOT * 4);
    uint32_t* ST3 = (uint32_t*)take((size_t)4 * MTOT * 4);
    float*    syn4 = (float*)take((size_t)MTOT * 2 * 4);
    unsigned int* cnts = (unsigned int*)take(256);
    uint32_t* list0 = (uint32_t*)take((size_t)NB * 256 * 4);
    uint32_t* list1 = (uint32_t*)take((size_t)NB * 256 * 4);
    uint32_t* list2 = (uint32_t*)take((size_t)NB * 128 * 4);

    int chunk = NB;
    while (chunk > 128 && off + (size_t)chunk * 50 * 256 * 4 > ws_size) chunk >>= 1;
    float* syn = (float*)take((size_t)chunk * 50 * 256 * 4);

    hipMemsetAsync(cnts, 0, 12, stream);

    pack_w_kernel<<<256, 256, 0, stream>>>(fw1, Wg1, 216);
    pack_w_kernel<<<256, 256, 0, stream>>>(fw2, Wg2, 256);
    pack_w_kernel<<<128, 256, 0, stream>>>(fw3, Wg3, 256);

    conv1_kernel<<<NB, 192, 0, stream>>>(xscan, w1, b1, S1);
    conv2_kernel<<<NB, 128, 0, stream>>>((const unsigned int*)S1, w2, b2, S2);
    conv3_kernel<<<NB, 64, 0, stream>>>(S2, w3, b3, normal, ST0);

    for (int b0 = 0; b0 < NB; b0 += chunk) {
        mfma_fc_kernel<<<dim3(chunk * 50 / 128, 2), 256, 0, stream>>>(
            ST0, Wg1, fb1, syn, 256, b0 * 50);
        fc_scan_flag_kernel<256><<<chunk, 256, 0, stream>>>(syn, ST1, b0, list0, cnts + 0);
        repair_kernel<7, 216><<<512, 256, 0, stream>>>(ST0, fw1, fb1, ST1, list0, cnts + 0);

        mfma_fc_kernel<<<dim3(chunk * 50 / 128, 2), 256, 0, stream>>>(
            ST1, Wg2, fb2, syn, 256, b0 * 50);
        fc_scan_flag_kernel<256><<<chunk, 256, 0, stream>>>(syn, ST2, b0, list1, cnts + 1);
        repair_kernel<8, 256><<<512, 256, 0, stream>>>(ST1, fw2, fb2, ST2, list1, cnts + 1);

        mfma_fc_kernel<<<dim3(chunk * 50 / 128, 1), 256, 0, stream>>>(
            ST2, Wg3, fb3, syn, 128, b0 * 50);
        fc_scan_flag_kernel<128><<<chunk, 128, 0, stream>>>(syn, ST3, b0, list2, cnts + 2);
        repair_kernel<8, 256><<<512, 256, 0, stream>>>(ST2, fw3, fb3, ST3, list2, cnts + 2);
    }

    fc4_gemm_kernel<<<MTOT / 256, 256, 0, stream>>>(ST3, fw4, fb4, syn4);
    fc4_scan_kernel<<<NB / 64, 64, 0, stream>>>(syn4, out);
}

// Round 10
// 1710.273 us; speedup vs baseline: 1.0608x; 1.0418x over previous
//
#include <hip/hip_runtime.h>
#include <cstdint>
#include <cstddef>

// ---------------------------------------------------------------------------
// ActorNetSpiking: layer-by-layer over time; spikes bit-packed in transposed
// u32 planes. FC layers: bf16x3-split MFMA GEMM (fast, provisional) + LIF
// scan that FLAGS neurons with any |v-0.5| < DELTA + exact-repair kernel
// (ascending-k single-accumulator f32 fmaf chain, the validated reference
// order). Convs use register-lean q-outer/o-inner exact chains.
// ---------------------------------------------------------------------------

#define NB 4096
#define MTOT (NB * 50)
#define DELTA 1e-3f

typedef __attribute__((ext_vector_type(8))) short bf16x8;
typedef __attribute__((ext_vector_type(4))) float f32x4;
typedef __attribute__((ext_vector_type(4))) uint32_t u32x4;

__device__ __forceinline__ void neuron_update(float syn, float& u, float& v, float& s) {
    u = u * 0.5f + syn;
    v = v * 0.75f * (1.0f - s) + u;
    s = (v > 0.5f) ? 1.0f : 0.0f;
}

// ------------------------- conv1: (B,1,360) -> (B,5,178) --------------------
__global__ __launch_bounds__(192) void conv1_kernel(
    const float* __restrict__ x, const float* __restrict__ w1,
    const float* __restrict__ b1, unsigned long long* __restrict__ S1)
{
    __shared__ float xl[9000];
    const int tid = threadIdx.x;
    const int b = blockIdx.x;
    const int j = tid;
    const int lbase = (j < 178) ? 2 * j : 354;

    float wr[25], br[5];
#pragma unroll
    for (int q = 0; q < 25; ++q) wr[q] = w1[q];
#pragma unroll
    for (int o = 0; o < 5; ++o) br[o] = b1[o];

    float u[5], v[5], s[5];
#pragma unroll
    for (int o = 0; o < 5; ++o) { u[o] = 0.f; v[o] = 0.f; s[o] = 0.f; }

    const float* xb = x + (size_t)b * 18000;
    for (int half = 0; half < 2; ++half) {
        const int t0 = half * 25;
        __syncthreads();
        for (int e = tid; e < 9000; e += 192)
            xl[e] = xb[(e / 25) * 50 + t0 + (e % 25)];
        __syncthreads();
        for (int dt = 0; dt < 25; ++dt) {
            const int t = t0 + dt;
            float acc[5];
#pragma unroll
            for (int o = 0; o < 5; ++o) acc[o] = 0.f;
            // k-outer / o-inner: each acc[o] accumulates k ascending (exact)
#pragma unroll
            for (int k = 0; k < 5; ++k) {
                const float xk = xl[(lbase + k) * 25 + dt];
#pragma unroll
                for (int o = 0; o < 5; ++o)
                    acc[o] = fmaf(wr[o * 5 + k], xk, acc[o]);
            }
#pragma unroll
            for (int o = 0; o < 5; ++o) {
                const float syn = acc[o] + br[o];
                neuron_update(syn, u[o], v[o], s[o]);
                unsigned long long m = __ballot(j < 178 && s[o] > 0.5f);
                if ((tid & 63) == 0)
                    S1[(((size_t)b * 50 + t) * 5 + o) * 3 + (tid >> 6)] = m;
            }
        }
    }
}

// ------------------------- conv2: (B,5,178) -> (B,5,87) ---------------------
__global__ __launch_bounds__(128) void conv2_kernel(
    const unsigned int* __restrict__ S1, const float* __restrict__ w2,
    const float* __restrict__ b2, unsigned int* __restrict__ S2)
{
    __shared__ unsigned int s1l[1501];
    const int tid = threadIdx.x;
    const int b = blockIdx.x;

    float wr[125], br[5];
#pragma unroll
    for (int q = 0; q < 125; ++q) wr[q] = w2[q];
#pragma unroll
    for (int o = 0; o < 5; ++o) br[o] = b2[o];

    const unsigned int* src = S1 + (size_t)b * 1500;
    for (int e = tid; e < 1500; e += 128) s1l[e] = src[e];
    __syncthreads();

    const int p = (tid < 87) ? 2 * tid : 172;
    const int pw = p >> 5, ps = p & 31;

    float u[5], v[5], s[5];
#pragma unroll
    for (int o = 0; o < 5; ++o) { u[o] = 0.f; v[o] = 0.f; s[o] = 0.f; }

    for (int t = 0; t < 50; ++t) {
        float acc[5];
#pragma unroll
        for (int o = 0; o < 5; ++o) acc[o] = 0.f;
        // q = ci*5+k ascending per acc[o] chain: exact validated order
#pragma unroll
        for (int ci = 0; ci < 5; ++ci) {
            const int base = (t * 5 + ci) * 6 + pw;
            const unsigned int w5 = (unsigned int)(
                ((((unsigned long long)s1l[base + 1]) << 32) |
                 (unsigned long long)s1l[base]) >> ps);
#pragma unroll
            for (int k = 0; k < 5; ++k) {
                const float xk = (float)((w5 >> k) & 1u);
#pragma unroll
                for (int o = 0; o < 5; ++o)
                    acc[o] = fmaf(wr[o * 25 + ci * 5 + k], xk, acc[o]);
            }
        }
#pragma unroll
        for (int o = 0; o < 5; ++o) {
            const float syn = acc[o] + br[o];
            neuron_update(syn, u[o], v[o], s[o]);
            unsigned long long m = __ballot(tid < 87 && s[o] > 0.5f);
            const size_t outb = (((size_t)b * 50 + t) * 5 + o) * 3;
            if (tid == 0) {
                S2[outb]     = (unsigned int)m;
                S2[outb + 1] = (unsigned int)(m >> 32);
            }
            if (tid == 64) S2[outb + 2] = (unsigned int)m;
        }
    }
}

// ------------------------- conv3: (B,5,87) -> transposed 216-bit rows -------
// 2 batch elements per 128-thread block (wave = one b). Bits k=0..209 conv3
// spikes (k=o*42+j), 210..215 normal. Planes 0..6 data, plane 7 zero.
__global__ __launch_bounds__(128) void conv3_kernel(
    const unsigned int* __restrict__ S2, const float* __restrict__ w3,
    const float* __restrict__ b3, const float* __restrict__ normal,
    unsigned int* __restrict__ ST0)
{
    __shared__ unsigned int s2l[2][751];
    const int tid = threadIdx.x;
    const int wv = tid >> 6;
    const int lane = tid & 63;
    const int b = blockIdx.x * 2 + wv;

    float wr[125], br[5];
#pragma unroll
    for (int q = 0; q < 125; ++q) wr[q] = w3[q];
#pragma unroll
    for (int o = 0; o < 5; ++o) br[o] = b3[o];

    unsigned int* sl = s2l[wv];
    const unsigned int* src = S2 + (size_t)b * 750;
    for (int e = lane; e < 750; e += 64) sl[e] = src[e];
    __syncthreads();

    const int p = (lane < 42) ? 2 * lane : 82;
    const int pw = p >> 5, ps = p & 31;

    float u[5], v[5], s[5];
#pragma unroll
    for (int o = 0; o < 5; ++o) { u[o] = 0.f; v[o] = 0.f; s[o] = 0.f; }

    for (int t = 0; t < 50; ++t) {
        float acc[5];
#pragma unroll
        for (int o = 0; o < 5; ++o) acc[o] = 0.f;
#pragma unroll
        for (int ci = 0; ci < 5; ++ci) {
            const int base = (t * 5 + ci) * 3 + pw;
            const unsigned int w5 = (unsigned int)(
                ((((unsigned long long)sl[base + 1]) << 32) |
                 (unsigned long long)sl[base]) >> ps);
#pragma unroll
            for (int k = 0; k < 5; ++k) {
                const float xk = (float)((w5 >> k) & 1u);
#pragma unroll
                for (int o = 0; o < 5; ++o)
                    acc[o] = fmaf(wr[o * 25 + ci * 5 + k], xk, acc[o]);
            }
        }
        unsigned long long m[5];
#pragma unroll
        for (int o = 0; o < 5; ++o) {
            const float syn = acc[o] + br[o];
            neuron_update(syn, u[o], v[o], s[o]);
            m[o] = __ballot(lane < 42 && s[o] > 0.5f);
        }
        const unsigned long long nm =
            __ballot(lane < 6 && normal[((size_t)b * 6 + lane) * 50 + t] > 0.5f);
        if (lane == 0) {
            const unsigned long long r0 = m[0] | (m[1] << 42);
            const unsigned long long r1 = (m[1] >> 22) | (m[2] << 20) | (m[3] << 62);
            const unsigned long long r2 = (m[3] >> 2) | (m[4] << 40);
            const unsigned long long r3 = (m[4] >> 24) | (nm << 18);
            const size_t mrow = (size_t)b * 50 + t;
            ST0[0 * (size_t)MTOT + mrow] = (unsigned int)r0;
            ST0[1 * (size_t)MTOT + mrow] = (unsigned int)(r0 >> 32);
            ST0[2 * (size_t)MTOT + mrow] = (unsigned int)r1;
            ST0[3 * (size_t)MTOT + mrow] = (unsigned int)(r1 >> 32);
            ST0[4 * (size_t)MTOT + mrow] = (unsigned int)r2;
            ST0[5 * (size_t)MTOT + mrow] = (unsigned int)(r2 >> 32);
            ST0[6 * (size_t)MTOT + mrow] = (unsigned int)r3;
            ST0[7 * (size_t)MTOT + mrow] = 0u;
        }
    }
}

// ------------------------- weight split+swizzle prep (validated r2) ---------
__global__ __launch_bounds__(256) void pack_w_kernel(
    const float* __restrict__ W, unsigned short* __restrict__ dst, int KREAL)
{
    const int idx = blockIdx.x * 256 + threadIdx.x;
    const int n = idx >> 8, k = idx & 255;
    const float w = (k < KREAL) ? W[(size_t)n * KREAL + k] : 0.f;
    const uint32_t u0 = __float_as_uint(w);
    const unsigned short h0 = (unsigned short)(u0 >> 16);
    const float p0 = __uint_as_float(u0 & 0xFFFF0000u);
    const float r1 = w - p0;
    const uint32_t u1 = __float_as_uint(r1);
    const unsigned short h1 = (unsigned short)(u1 >> 16);
    const float p1 = __uint_as_float(u1 & 0xFFFF0000u);
    const float r2 = r1 - p1;
    const unsigned short h2 = (unsigned short)(__float_as_uint(r2) >> 16);

    const int nb = n >> 7, row = n & 127;
    const int kc = k >> 6, kl = k & 63;
    const int kbyte = (kl * 2) ^ ((row & 7) << 4);
    const size_t base = ((size_t)nb * 12 + (size_t)kc * 3) * 8192 + row * 64 + (kbyte >> 1);
    dst[base] = h0;
    dst[base + 8192] = h1;
    dst[base + 16384] = h2;
}

// ------------------------- MFMA FC GEMM (validated r2/r9 structure) ---------
__global__ __launch_bounds__(256, 3) void mfma_fc_kernel(
    const uint32_t* __restrict__ bitsT,       // planes [8][MTOT]
    const unsigned short* __restrict__ wg,    // pre-swizzled tiles
    const float* __restrict__ bias,
    float* __restrict__ syn,                  // [Mchunk][Ntot]
    int Ntot, int row0)
{
    __shared__ __align__(16) unsigned short blds[3][8192];  // 3 x 16KB
    __shared__ __align__(16) uint32_t bits_lds[1024];       // [plane w][128 m]

    const int tid = threadIdx.x;
    const int lane = tid & 63;
    const int wid = tid >> 6;
    const int wm = wid >> 1, wn = wid & 1;
    const int m0 = blockIdx.x * 128;
    const int nb = blockIdx.y;
    const int nbase = nb * 128;

    {
        const uint32_t* g = bitsT + (size_t)(tid >> 5) * MTOT + (row0 + m0) + (tid & 31) * 4;
        uint32_t* l = bits_lds + wid * 256;
        __builtin_amdgcn_global_load_lds(
            (const __attribute__((address_space(1))) uint32_t*)g,
            (__attribute__((address_space(3))) uint32_t*)l, 16, 0, 0);
    }

    auto stage = [&](int t_idx, int buf) {
        const unsigned short* wt = wg + ((size_t)(nb * 12 + t_idx)) * 8192;
#pragma unroll
        for (int j = 0; j < 4; ++j) {
            const char* g = (const char*)wt + j * 4096 + wid * 1024 + lane * 16;
            char* l = (char*)&blds[buf][0] + j * 4096 + wid * 1024;
            __builtin_amdgcn_global_load_lds(
                (const __attribute__((address_space(1))) uint32_t*)g,
                (__attribute__((address_space(3))) uint32_t*)l, 16, 0, 0);
        }
    };

    stage(0, 0);
    stage(1, 1);

    f32x4 acc[4][4];
#pragma unroll
    for (int i = 0; i < 4; ++i)
#pragma unroll
        for (int j = 0; j < 4; ++j) acc[i][j] = (f32x4){0.f, 0.f, 0.f, 0.f};

    union frag { u32x4 u; bf16x8 h; };
    frag afr[4][2];

#pragma unroll
    for (int s = 0; s < 12; ++s) {
        if (s < 11) asm volatile("s_waitcnt vmcnt(4)\ns_barrier" ::: "memory");
        else        asm volatile("s_waitcnt vmcnt(0)\ns_barrier" ::: "memory");
        if (s + 2 < 12) stage(s + 2, (s + 2) % 3);

        const int kc = s / 3;
        if ((s % 3) == 0) {
#pragma unroll
            for (int mi = 0; mi < 4; ++mi) {
                const int row = wm * 64 + mi * 16 + (lane & 15);
#pragma unroll
                for (int kk = 0; kk < 2; ++kk) {
                    const uint32_t wbits = bits_lds[(kc * 2 + kk) * 128 + row];
                    const uint32_t bb = (wbits >> ((lane >> 4) * 8)) & 0xFFu;
                    u32x4 e;
#pragma unroll
                    for (int j = 0; j < 4; ++j) {
                        uint32_t r = ((bb >> (2 * j)) & 1u) ? 0x3F80u : 0u;
                        if ((bb >> (2 * j + 1)) & 1u) r |= 0x3F800000u;
                        e[j] = r;
                    }
                    afr[mi][kk].u = e;
                }
            }
        }

        const char* bt = (const char*)&blds[s % 3][0];
        __builtin_amdgcn_s_setprio(1);
#pragma unroll
        for (int kk = 0; kk < 2; ++kk) {
#pragma unroll
            for (int ni = 0; ni < 4; ++ni) {
                const int r = wn * 64 + ni * 16 + (lane & 15);
                const int kb = kk * 64 + (lane >> 4) * 16;
                const int off = r * 128 + (kb ^ ((r & 7) << 4));
                bf16x8 bfr = *reinterpret_cast<const bf16x8*>(bt + off);
#pragma unroll
                for (int mi = 0; mi < 4; ++mi)
                    acc[mi][ni] = __builtin_amdgcn_mfma_f32_16x16x32_bf16(
                        afr[mi][kk].h, bfr, acc[mi][ni], 0, 0, 0);
            }
        }
        __builtin_amdgcn_s_setprio(0);
    }

#pragma unroll
    for (int ni = 0; ni < 4; ++ni) {
        const int n = nbase + wn * 64 + ni * 16 + (lane & 15);
        const float bs = bias[n];
#pragma unroll
        for (int mi = 0; mi < 4; ++mi) {
            const int mr = m0 + wm * 64 + mi * 16 + ((lane >> 4) << 2);
            float* dst = syn + (size_t)mr * Ntot + n;
            f32x4 a = acc[mi][ni];
#pragma unroll
            for (int rr = 0; rr < 4; ++rr) dst[(size_t)rr * Ntot] = a[rr] + bs;
        }
    }
}

// ------------------------- FC scan + flag: LIF -> planes + repair list ------
template <int N>
__global__ __launch_bounds__(N) void fc_scan_flag_kernel(
    const float* __restrict__ syn,        // [chunk*50][N]
    uint32_t* __restrict__ SFT,           // planes [N/32][MTOT]
    int b0,
    uint32_t* __restrict__ list, unsigned int* __restrict__ cnt)
{
    const int tid = threadIdx.x;
    const int lane = tid & 63;
    const int ob = tid >> 6;
    const int bl = blockIdx.x;
    const int o = tid;

    float u = 0.f, v = 0.f, s = 0.f;
    bool flag = false;
    for (int t = 0; t < 50; ++t) {
        const float sv = syn[((size_t)bl * 50 + t) * N + o];
        u = u * 0.5f + sv;
        v = v * 0.75f * (1.0f - s) + u;
        flag |= (fabsf(v - 0.5f) < DELTA);
        s = (v > 0.5f) ? 1.0f : 0.0f;
        const unsigned long long m = __ballot(s > 0.5f);
        if (lane == 0) {
            const size_t row = (size_t)(b0 + bl) * 50 + t;
            SFT[(size_t)(2 * ob) * MTOT + row]     = (uint32_t)m;
            SFT[(size_t)(2 * ob + 1) * MTOT + row] = (uint32_t)(m >> 32);
        }
    }
    const unsigned long long fm = __ballot(flag);
    unsigned int base = 0;
    if (lane == 0 && fm) base = atomicAdd(cnt, (unsigned int)__popcll(fm));
    base = __shfl(base, 0);
    if (flag) {
        const unsigned int off = (unsigned int)__popcll(fm & ((1ULL << lane) - 1ULL));
        list[base + off] = ((unsigned int)(b0 + bl) << 8) | (unsigned int)o;
    }
}

// ------------------------- exact repair: flagged neurons --------------------
template <int KT, int KREAL>
__global__ __launch_bounds__(256) void repair_kernel(
    const uint32_t* __restrict__ planesIn,   // [KT..8][MTOT]
    const float* __restrict__ W,             // (NOUT, KREAL) row-major
    const float* __restrict__ bias,
    uint32_t* __restrict__ planesOut,        // [NOUT/32][MTOT]
    const uint32_t* __restrict__ list,
    const unsigned int* __restrict__ cnt)
{
    const int lane = threadIdx.x & 63;
    const int wid = blockIdx.x * 4 + (threadIdx.x >> 6);
    const int nwaves = gridDim.x * 4;
    const unsigned int n = *cnt;

    for (unsigned int idx = wid; idx < n; idx += nwaves) {
        const uint32_t e = list[idx];
        const int b = __builtin_amdgcn_readfirstlane((int)(e >> 8));
        const int o = __builtin_amdgcn_readfirstlane((int)(e & 255u));
        const int tl = (lane < 50) ? lane : 49;
        const size_t row = (size_t)b * 50 + tl;

        uint32_t wb[KT];
#pragma unroll
        for (int w = 0; w < KT; ++w) wb[w] = planesIn[(size_t)w * MTOT + row];

        const float* wr = W + (size_t)o * KREAL;
        float acc = 0.f;
#pragma unroll
        for (int kt = 0; kt < KT; ++kt) {
#pragma unroll
            for (int kk = 0; kk < 32; ++kk) {
                const int k = kt * 32 + kk;
                if (k < KREAL)
                    acc = fmaf((float)((wb[kt] >> kk) & 1u), wr[k], acc);
            }
        }
        const float syn_t = acc + bias[o];

        float u = 0.f, v = 0.f, s = 0.f, mys = 0.f;
#pragma unroll 1
        for (int t = 0; t < 50; ++t) {
            const float sv = __shfl(syn_t, t);
            u = u * 0.5f + sv;
            v = v * 0.75f * (1.0f - s) + u;
            s = (v > 0.5f) ? 1.0f : 0.0f;
            if (lane == t) mys = s;
        }

        if (lane < 50) {
            uint32_t* wp = planesOut + (size_t)(o >> 5) * MTOT + row;
            const uint32_t bit = 1u << (o & 31);
            const bool prov = (*wp & bit) != 0u;
            const bool ex = (mys > 0.5f);
            if (prov != ex) atomicXor(wp, bit);
        }
    }
}

// ------------------------- fc4 GEMM (N=2, K=128, exact) ---------------------
__global__ __launch_bounds__(256) void fc4_gemm_kernel(
    const uint32_t* __restrict__ P3,          // planes [4][MTOT]
    const float* __restrict__ W, const float* __restrict__ bias,
    float* __restrict__ syn4)
{
    const int m = blockIdx.x * 256 + threadIdx.x;
    const unsigned long long w0 =
        (unsigned long long)P3[m] | ((unsigned long long)P3[(size_t)MTOT + m] << 32);
    const unsigned long long w1 =
        (unsigned long long)P3[2 * (size_t)MTOT + m] |
        ((unsigned long long)P3[3 * (size_t)MTOT + m] << 32);
    float a0 = 0.f, a1 = 0.f;
#pragma unroll
    for (int i = 0; i < 64; ++i) {
        const float bit = ((w0 >> i) & 1ULL) ? 1.f : 0.f;
        a0 = fmaf(bit, W[i], a0);
        a1 = fmaf(bit, W[128 + i], a1);
    }
#pragma unroll
    for (int i = 0; i < 64; ++i) {
        const float bit = ((w1 >> i) & 1ULL) ? 1.f : 0.f;
        a0 = fmaf(bit, W[64 + i], a0);
        a1 = fmaf(bit, W[192 + i], a1);
    }
    syn4[(size_t)m * 2]     = a0 + bias[0];
    syn4[(size_t)m * 2 + 1] = a1 + bias[1];
}

__global__ __launch_bounds__(64) void fc4_scan_kernel(
    const float* __restrict__ syn4, float* __restrict__ out)
{
    const int b = blockIdx.x * 64 + threadIdx.x;
    float u0 = 0.f, v0 = 0.f, s0 = 0.f, acc0 = 0.f;
    float u1 = 0.f, v1 = 0.f, s1 = 0.f, acc1 = 0.f;
    for (int t = 0; t < 50; ++t) {
        const float x0 = syn4[((size_t)b * 50 + t) * 2];
        const float x1 = syn4[((size_t)b * 50 + t) * 2 + 1];
        neuron_update(x0, u0, v0, s0); acc0 += s0;
        neuron_update(x1, u1, v1, s1); acc1 += s1;
    }
    out[b * 2]     = acc0 / 50.0f;
    out[b * 2 + 1] = acc1 / 50.0f;
}

// ---------------------------------------------------------------------------
extern "C" void kernel_launch(void* const* d_in, const int* in_sizes, int n_in,
                              void* d_out, int out_size, void* d_ws, size_t ws_size,
                              hipStream_t stream) {
    (void)in_sizes; (void)n_in; (void)out_size;
    const float* normal = (const float*)d_in[0];
    const float* xscan  = (const float*)d_in[1];
    const float* w1  = (const float*)d_in[3];
    const float* b1  = (const float*)d_in[4];
    const float* w2  = (const float*)d_in[5];
    const float* b2  = (const float*)d_in[6];
    const float* w3  = (const float*)d_in[7];
    const float* b3  = (const float*)d_in[8];
    const float* fw1 = (const float*)d_in[9];
    const float* fb1 = (const float*)d_in[10];
    const float* fw2 = (const float*)d_in[11];
    const float* fb2 = (const float*)d_in[12];
    const float* fw3 = (const float*)d_in[13];
    const float* fb3 = (const float*)d_in[14];
    const float* fw4 = (const float*)d_in[15];
    const float* fb4 = (const float*)d_in[16];
    float* out = (float*)d_out;

    char* wp = (char*)d_ws;
    size_t off = 0;
    auto take = [&](size_t bytes) -> void* {
        void* p = wp + off;
        off += (bytes + 255) & ~(size_t)255;
        return p;
    };
    unsigned short* Wg1 = (unsigned short*)take((size_t)2 * 12 * 8192 * 2);
    unsigned short* Wg2 = (unsigned short*)take((size_t)2 * 12 * 8192 * 2);
    unsigned short* Wg3 = (unsigned short*)take((size_t)1 * 12 * 8192 * 2);
    unsigned long long* S1  = (unsigned long long*)take((size_t)NB * 50 * 15 * 8);
    unsigned int*       S2  = (unsigned int*)take((size_t)NB * 50 * 15 * 4);
    uint32_t* ST0 = (uint32_t*)take((size_t)8 * MTOT * 4);
    uint32_t* ST1 = (uint32_t*)take((size_t)8 * MTOT * 4);
    uint32_t* ST2 = (uint32_t*)take((size_t)8 * MTOT * 4);
    uint32_t* ST3 = (uint32_t*)take((size_t)4 * MTOT * 4);
    float*    syn4 = (float*)take((size_t)MTOT * 2 * 4);
    unsigned int* cnts = (unsigned int*)take(256);
    uint32_t* list0 = (uint32_t*)take((size_t)NB * 256 * 4);
    uint32_t* list1 = (uint32_t*)take((size_t)NB * 256 * 4);
    uint32_t* list2 = (uint32_t*)take((size_t)NB * 128 * 4);

    int chunk = NB;
    while (chunk > 128 && off + (size_t)chunk * 50 * 256 * 4 > ws_size) chunk >>= 1;
    float* syn = (float*)take((size_t)chunk * 50 * 256 * 4);

    hipMemsetAsync(cnts, 0, 12, stream);

    pack_w_kernel<<<256, 256, 0, stream>>>(fw1, Wg1, 216);
    pack_w_kernel<<<256, 256, 0, stream>>>(fw2, Wg2, 256);
    pack_w_kernel<<<128, 256, 0, stream>>>(fw3, Wg3, 256);

    conv1_kernel<<<NB, 192, 0, stream>>>(xscan, w1, b1, S1);
    conv2_kernel<<<NB, 128, 0, stream>>>((const unsigned int*)S1, w2, b2, S2);
    conv3_kernel<<<NB / 2, 128, 0, stream>>>(S2, w3, b3, normal, ST0);

    for (int b0 = 0; b0 < NB; b0 += chunk) {
        mfma_fc_kernel<<<dim3(chunk * 50 / 128, 2), 256, 0, stream>>>(
            ST0, Wg1, fb1, syn, 256, b0 * 50);
        fc_scan_flag_kernel<256><<<chunk, 256, 0, stream>>>(syn, ST1, b0, list0, cnts + 0);
        repair_kernel<7, 216><<<512, 256, 0, stream>>>(ST0, fw1, fb1, ST1, list0, cnts + 0);

        mfma_fc_kernel<<<dim3(chunk * 50 / 128, 2), 256, 0, stream>>>(
            ST1, Wg2, fb2, syn, 256, b0 * 50);
        fc_scan_flag_kernel<256><<<chunk, 256, 0, stream>>>(syn, ST2, b0, list1, cnts + 1);
        repair_kernel<8, 256><<<512, 256, 0, stream>>>(ST1, fw2, fb2, ST2, list1, cnts + 1);

        mfma_fc_kernel<<<dim3(chunk * 50 / 128, 1), 256, 0, stream>>>(
            ST2, Wg3, fb3, syn, 128, b0 * 50);
        fc_scan_flag_kernel<128><<<chunk, 128, 0, stream>>>(syn, ST3, b0, list2, cnts + 2);
        repair_kernel<8, 256><<<512, 256, 0, stream>>>(ST2, fw3, fb3, ST3, list2, cnts + 2);
    }

    fc4_gemm_kernel<<<MTOT / 256, 256, 0, stream>>>(ST3, fw4, fb4, syn4);
    fc4_scan_kernel<<<NB / 64, 64, 0, stream>>>(syn4, out);
}

// Round 11
// 1629.246 us; speedup vs baseline: 1.1136x; 1.0497x over previous
//
#include <hip/hip_runtime.h>
#include <cstdint>
#include <cstddef>

// ---------------------------------------------------------------------------
// ActorNetSpiking: layer-by-layer over time; spikes bit-packed in transposed
// u32 planes. FC layers: bf16x3-split MFMA GEMM (fast, provisional) + LIF
// scan that FLAGS neurons with any |v-0.5| < DELTA + exact-repair kernel
// (ascending-k single-accumulator f32 fmaf chain, the validated reference
// order). Convs: register-PINNED weights (asm "+v" defeats the compiler's
// reload-instead-of-keep-live heuristic seen as VGPR_Count=28).
// ---------------------------------------------------------------------------

#define NB 4096
#define MTOT (NB * 50)
#define DELTA 1e-3f

typedef __attribute__((ext_vector_type(8))) short bf16x8;
typedef __attribute__((ext_vector_type(4))) float f32x4;
typedef __attribute__((ext_vector_type(4))) uint32_t u32x4;

__device__ __forceinline__ void neuron_update(float syn, float& u, float& v, float& s) {
    u = u * 0.5f + syn;
    v = v * 0.75f * (1.0f - s) + u;
    s = (v > 0.5f) ? 1.0f : 0.0f;
}

// ------------------------- conv1: (B,1,360) -> (B,5,178) --------------------
__global__ __launch_bounds__(192) void conv1_kernel(
    const float* __restrict__ x, const float* __restrict__ w1,
    const float* __restrict__ b1, unsigned long long* __restrict__ S1)
{
    __shared__ float xl[9000];
    const int tid = threadIdx.x;
    const int b = blockIdx.x;
    const int j = tid;
    const int lbase = (j < 178) ? 2 * j : 354;

    float wr[25], br[5];
#pragma unroll
    for (int q = 0; q < 25; ++q) wr[q] = w1[q];
#pragma unroll
    for (int o = 0; o < 5; ++o) br[o] = b1[o];
    // pin weights in VGPRs (prevent per-iteration reload)
#pragma unroll
    for (int q = 0; q < 25; ++q) asm volatile("" : "+v"(wr[q]));
#pragma unroll
    for (int o = 0; o < 5; ++o) asm volatile("" : "+v"(br[o]));

    float u[5], v[5], s[5];
#pragma unroll
    for (int o = 0; o < 5; ++o) { u[o] = 0.f; v[o] = 0.f; s[o] = 0.f; }

    const float* xb = x + (size_t)b * 18000;
    for (int half = 0; half < 2; ++half) {
        const int t0 = half * 25;
        __syncthreads();
        for (int e = tid; e < 9000; e += 192)
            xl[e] = xb[(e / 25) * 50 + t0 + (e % 25)];
        __syncthreads();
        for (int dt = 0; dt < 25; ++dt) {
            const int t = t0 + dt;
            float acc[5];
#pragma unroll
            for (int o = 0; o < 5; ++o) acc[o] = 0.f;
#pragma unroll
            for (int k = 0; k < 5; ++k) {
                const float xk = xl[(lbase + k) * 25 + dt];
#pragma unroll
                for (int o = 0; o < 5; ++o)
                    acc[o] = fmaf(wr[o * 5 + k], xk, acc[o]);
            }
#pragma unroll
            for (int o = 0; o < 5; ++o) {
                const float syn = acc[o] + br[o];
                neuron_update(syn, u[o], v[o], s[o]);
                unsigned long long m = __ballot(j < 178 && s[o] > 0.5f);
                if ((tid & 63) == 0)
                    S1[(((size_t)b * 50 + t) * 5 + o) * 3 + (tid >> 6)] = m;
            }
        }
    }
}

// ------------------------- conv2: (B,5,178) -> (B,5,87) ---------------------
__global__ __launch_bounds__(128) void conv2_kernel(
    const unsigned int* __restrict__ S1, const float* __restrict__ w2,
    const float* __restrict__ b2, unsigned int* __restrict__ S2)
{
    __shared__ unsigned int s1l[1501];
    const int tid = threadIdx.x;
    const int b = blockIdx.x;

    float wr[125], br[5];
#pragma unroll
    for (int q = 0; q < 125; ++q) wr[q] = w2[q];
#pragma unroll
    for (int o = 0; o < 5; ++o) br[o] = b2[o];
    // pin all 130 weights/biases in VGPRs
#pragma unroll
    for (int q = 0; q < 125; ++q) asm volatile("" : "+v"(wr[q]));
#pragma unroll
    for (int o = 0; o < 5; ++o) asm volatile("" : "+v"(br[o]));

    const unsigned int* src = S1 + (size_t)b * 1500;
    for (int e = tid; e < 1500; e += 128) s1l[e] = src[e];
    __syncthreads();

    const int p = (tid < 87) ? 2 * tid : 172;
    const int pw = p >> 5, ps = p & 31;

    float u[5], v[5], s[5];
#pragma unroll
    for (int o = 0; o < 5; ++o) { u[o] = 0.f; v[o] = 0.f; s[o] = 0.f; }

    for (int t = 0; t < 50; ++t) {
        float acc[5];
#pragma unroll
        for (int o = 0; o < 5; ++o) acc[o] = 0.f;
#pragma unroll
        for (int ci = 0; ci < 5; ++ci) {
            const int base = (t * 5 + ci) * 6 + pw;
            const unsigned int w5 = (unsigned int)(
                ((((unsigned long long)s1l[base + 1]) << 32) |
                 (unsigned long long)s1l[base]) >> ps);
#pragma unroll
            for (int k = 0; k < 5; ++k) {
                const float xk = (float)((w5 >> k) & 1u);
#pragma unroll
                for (int o = 0; o < 5; ++o)
                    acc[o] = fmaf(wr[o * 25 + ci * 5 + k], xk, acc[o]);
            }
        }
#pragma unroll
        for (int o = 0; o < 5; ++o) {
            const float syn = acc[o] + br[o];
            neuron_update(syn, u[o], v[o], s[o]);
            unsigned long long m = __ballot(tid < 87 && s[o] > 0.5f);
            const size_t outb = (((size_t)b * 50 + t) * 5 + o) * 3;
            if (tid == 0) {
                S2[outb]     = (unsigned int)m;
                S2[outb + 1] = (unsigned int)(m >> 32);
            }
            if (tid == 64) S2[outb + 2] = (unsigned int)m;
        }
    }
}

// ------------------------- conv3: (B,5,87) -> transposed 216-bit rows -------
__global__ __launch_bounds__(128) void conv3_kernel(
    const unsigned int* __restrict__ S2, const float* __restrict__ w3,
    const float* __restrict__ b3, const float* __restrict__ normal,
    unsigned int* __restrict__ ST0)
{
    __shared__ unsigned int s2l[2][751];
    const int tid = threadIdx.x;
    const int wv = tid >> 6;
    const int lane = tid & 63;
    const int b = blockIdx.x * 2 + wv;

    float wr[125], br[5];
#pragma unroll
    for (int q = 0; q < 125; ++q) wr[q] = w3[q];
#pragma unroll
    for (int o = 0; o < 5; ++o) br[o] = b3[o];
#pragma unroll
    for (int q = 0; q < 125; ++q) asm volatile("" : "+v"(wr[q]));
#pragma unroll
    for (int o = 0; o < 5; ++o) asm volatile("" : "+v"(br[o]));

    unsigned int* sl = s2l[wv];
    const unsigned int* src = S2 + (size_t)b * 750;
    for (int e = lane; e < 750; e += 64) sl[e] = src[e];
    __syncthreads();

    const int p = (lane < 42) ? 2 * lane : 82;
    const int pw = p >> 5, ps = p & 31;

    float u[5], v[5], s[5];
#pragma unroll
    for (int o = 0; o < 5; ++o) { u[o] = 0.f; v[o] = 0.f; s[o] = 0.f; }

    for (int t = 0; t < 50; ++t) {
        float acc[5];
#pragma unroll
        for (int o = 0; o < 5; ++o) acc[o] = 0.f;
#pragma unroll
        for (int ci = 0; ci < 5; ++ci) {
            const int base = (t * 5 + ci) * 3 + pw;
            const unsigned int w5 = (unsigned int)(
                ((((unsigned long long)sl[base + 1]) << 32) |
                 (unsigned long long)sl[base]) >> ps);
#pragma unroll
            for (int k = 0; k < 5; ++k) {
                const float xk = (float)((w5 >> k) & 1u);
#pragma unroll
                for (int o = 0; o < 5; ++o)
                    acc[o] = fmaf(wr[o * 25 + ci * 5 + k], xk, acc[o]);
            }
        }
        unsigned long long m[5];
#pragma unroll
        for (int o = 0; o < 5; ++o) {
            const float syn = acc[o] + br[o];
            neuron_update(syn, u[o], v[o], s[o]);
            m[o] = __ballot(lane < 42 && s[o] > 0.5f);
        }
        const unsigned long long nm =
            __ballot(lane < 6 && normal[((size_t)b * 6 + lane) * 50 + t] > 0.5f);
        if (lane == 0) {
            const unsigned long long r0 = m[0] | (m[1] << 42);
            const unsigned long long r1 = (m[1] >> 22) | (m[2] << 20) | (m[3] << 62);
            const unsigned long long r2 = (m[3] >> 2) | (m[4] << 40);
            const unsigned long long r3 = (m[4] >> 24) | (nm << 18);
            const size_t mrow = (size_t)b * 50 + t;
            ST0[0 * (size_t)MTOT + mrow] = (unsigned int)r0;
            ST0[1 * (size_t)MTOT + mrow] = (unsigned int)(r0 >> 32);
            ST0[2 * (size_t)MTOT + mrow] = (unsigned int)r1;
            ST0[3 * (size_t)MTOT + mrow] = (unsigned int)(r1 >> 32);
            ST0[4 * (size_t)MTOT + mrow] = (unsigned int)r2;
            ST0[5 * (size_t)MTOT + mrow] = (unsigned int)(r2 >> 32);
            ST0[6 * (size_t)MTOT + mrow] = (unsigned int)r3;
            ST0[7 * (size_t)MTOT + mrow] = 0u;
        }
    }
}

// ------------------------- weight split+swizzle prep (validated r2) ---------
__global__ __launch_bounds__(256) void pack_w_kernel(
    const float* __restrict__ W, unsigned short* __restrict__ dst, int KREAL)
{
    const int idx = blockIdx.x * 256 + threadIdx.x;
    const int n = idx >> 8, k = idx & 255;
    const float w = (k < KREAL) ? W[(size_t)n * KREAL + k] : 0.f;
    const uint32_t u0 = __float_as_uint(w);
    const unsigned short h0 = (unsigned short)(u0 >> 16);
    const float p0 = __uint_as_float(u0 & 0xFFFF0000u);
    const float r1 = w - p0;
    const uint32_t u1 = __float_as_uint(r1);
    const unsigned short h1 = (unsigned short)(u1 >> 16);
    const float p1 = __uint_as_float(u1 & 0xFFFF0000u);
    const float r2 = r1 - p1;
    const unsigned short h2 = (unsigned short)(__float_as_uint(r2) >> 16);

    const int nb = n >> 7, row = n & 127;
    const int kc = k >> 6, kl = k & 63;
    const int kbyte = (kl * 2) ^ ((row & 7) << 4);
    const size_t base = ((size_t)nb * 12 + (size_t)kc * 3) * 8192 + row * 64 + (kbyte >> 1);
    dst[base] = h0;
    dst[base + 8192] = h1;
    dst[base + 16384] = h2;
}

// ------------------------- MFMA FC GEMM (validated r2/r9 structure) ---------
__global__ __launch_bounds__(256, 3) void mfma_fc_kernel(
    const uint32_t* __restrict__ bitsT,       // planes [8][MTOT]
    const unsigned short* __restrict__ wg,    // pre-swizzled tiles
    const float* __restrict__ bias,
    float* __restrict__ syn,                  // [Mchunk][Ntot]
    int Ntot, int row0)
{
    __shared__ __align__(16) unsigned short blds[3][8192];  // 3 x 16KB
    __shared__ __align__(16) uint32_t bits_lds[1024];       // [plane w][128 m]

    const int tid = threadIdx.x;
    const int lane = tid & 63;
    const int wid = tid >> 6;
    const int wm = wid >> 1, wn = wid & 1;
    const int m0 = blockIdx.x * 128;
    const int nb = blockIdx.y;
    const int nbase = nb * 128;

    {
        const uint32_t* g = bitsT + (size_t)(tid >> 5) * MTOT + (row0 + m0) + (tid & 31) * 4;
        uint32_t* l = bits_lds + wid * 256;
        __builtin_amdgcn_global_load_lds(
            (const __attribute__((address_space(1))) uint32_t*)g,
            (__attribute__((address_space(3))) uint32_t*)l, 16, 0, 0);
    }

    auto stage = [&](int t_idx, int buf) {
        const unsigned short* wt = wg + ((size_t)(nb * 12 + t_idx)) * 8192;
#pragma unroll
        for (int j = 0; j < 4; ++j) {
            const char* g = (const char*)wt + j * 4096 + wid * 1024 + lane * 16;
            char* l = (char*)&blds[buf][0] + j * 4096 + wid * 1024;
            __builtin_amdgcn_global_load_lds(
                (const __attribute__((address_space(1))) uint32_t*)g,
                (__attribute__((address_space(3))) uint32_t*)l, 16, 0, 0);
        }
    };

    stage(0, 0);
    stage(1, 1);

    f32x4 acc[4][4];
#pragma unroll
    for (int i = 0; i < 4; ++i)
#pragma unroll
        for (int j = 0; j < 4; ++j) acc[i][j] = (f32x4){0.f, 0.f, 0.f, 0.f};

    union frag { u32x4 u; bf16x8 h; };
    frag afr[4][2];

#pragma unroll
    for (int s = 0; s < 12; ++s) {
        if (s < 11) asm volatile("s_waitcnt vmcnt(4)\ns_barrier" ::: "memory");
        else        asm volatile("s_waitcnt vmcnt(0)\ns_barrier" ::: "memory");
        if (s + 2 < 12) stage(s + 2, (s + 2) % 3);

        const int kc = s / 3;
        if ((s % 3) == 0) {
#pragma unroll
            for (int mi = 0; mi < 4; ++mi) {
                const int row = wm * 64 + mi * 16 + (lane & 15);
#pragma unroll
                for (int kk = 0; kk < 2; ++kk) {
                    const uint32_t wbits = bits_lds[(kc * 2 + kk) * 128 + row];
                    const uint32_t bb = (wbits >> ((lane >> 4) * 8)) & 0xFFu;
                    u32x4 e;
#pragma unroll
                    for (int j = 0; j < 4; ++j) {
                        uint32_t r = ((bb >> (2 * j)) & 1u) ? 0x3F80u : 0u;
                        if ((bb >> (2 * j + 1)) & 1u) r |= 0x3F800000u;
                        e[j] = r;
                    }
                    afr[mi][kk].u = e;
                }
            }
        }

        const char* bt = (const char*)&blds[s % 3][0];
        __builtin_amdgcn_s_setprio(1);
#pragma unroll
        for (int kk = 0; kk < 2; ++kk) {
#pragma unroll
            for (int ni = 0; ni < 4; ++ni) {
                const int r = wn * 64 + ni * 16 + (lane & 15);
                const int kb = kk * 64 + (lane >> 4) * 16;
                const int off = r * 128 + (kb ^ ((r & 7) << 4));
                bf16x8 bfr = *reinterpret_cast<const bf16x8*>(bt + off);
#pragma unroll
                for (int mi = 0; mi < 4; ++mi)
                    acc[mi][ni] = __builtin_amdgcn_mfma_f32_16x16x32_bf16(
                        afr[mi][kk].h, bfr, acc[mi][ni], 0, 0, 0);
            }
        }
        __builtin_amdgcn_s_setprio(0);
    }

#pragma unroll
    for (int ni = 0; ni < 4; ++ni) {
        const int n = nbase + wn * 64 + ni * 16 + (lane & 15);
        const float bs = bias[n];
#pragma unroll
        for (int mi = 0; mi < 4; ++mi) {
            const int mr = m0 + wm * 64 + mi * 16 + ((lane >> 4) << 2);
            float* dst = syn + (size_t)mr * Ntot + n;
            f32x4 a = acc[mi][ni];
#pragma unroll
            for (int rr = 0; rr < 4; ++rr) dst[(size_t)rr * Ntot] = a[rr] + bs;
        }
    }
}

// ------------------------- FC scan + flag: LIF -> planes + repair list ------
template <int N>
__global__ __launch_bounds__(N) void fc_scan_flag_kernel(
    const float* __restrict__ syn,        // [chunk*50][N]
    uint32_t* __restrict__ SFT,           // planes [N/32][MTOT]
    int b0,
    uint32_t* __restrict__ list, unsigned int* __restrict__ cnt)
{
    const int tid = threadIdx.x;
    const int lane = tid & 63;
    const int ob = tid >> 6;
    const int bl = blockIdx.x;
    const int o = tid;

    float u = 0.f, v = 0.f, s = 0.f;
    bool flag = false;
    for (int t = 0; t < 50; ++t) {
        const float sv = syn[((size_t)bl * 50 + t) * N + o];
        u = u * 0.5f + sv;
        v = v * 0.75f * (1.0f - s) + u;
        flag |= (fabsf(v - 0.5f) < DELTA);
        s = (v > 0.5f) ? 1.0f : 0.0f;
        const unsigned long long m = __ballot(s > 0.5f);
        if (lane == 0) {
            const size_t row = (size_t)(b0 + bl) * 50 + t;
            SFT[(size_t)(2 * ob) * MTOT + row]     = (uint32_t)m;
            SFT[(size_t)(2 * ob + 1) * MTOT + row] = (uint32_t)(m >> 32);
        }
    }
    const unsigned long long fm = __ballot(flag);
    unsigned int base = 0;
    if (lane == 0 && fm) base = atomicAdd(cnt, (unsigned int)__popcll(fm));
    base = __shfl(base, 0);
    if (flag) {
        const unsigned int off = (unsigned int)__popcll(fm & ((1ULL << lane) - 1ULL));
        list[base + off] = ((unsigned int)(b0 + bl) << 8) | (unsigned int)o;
    }
}

// ------------------------- exact repair: flagged neurons --------------------
template <int KT, int KREAL>
__global__ __launch_bounds__(256) void repair_kernel(
    const uint32_t* __restrict__ planesIn,   // [KT..8][MTOT]
    const float* __restrict__ W,             // (NOUT, KREAL) row-major
    const float* __restrict__ bias,
    uint32_t* __restrict__ planesOut,        // [NOUT/32][MTOT]
    const uint32_t* __restrict__ list,
    const unsigned int* __restrict__ cnt)
{
    const int lane = threadIdx.x & 63;
    const int wid = blockIdx.x * 4 + (threadIdx.x >> 6);
    const int nwaves = gridDim.x * 4;
    const unsigned int n = *cnt;

    for (unsigned int idx = wid; idx < n; idx += nwaves) {
        const uint32_t e = list[idx];
        const int b = __builtin_amdgcn_readfirstlane((int)(e >> 8));
        const int o = __builtin_amdgcn_readfirstlane((int)(e & 255u));
        const int tl = (lane < 50) ? lane : 49;
        const size_t row = (size_t)b * 50 + tl;

        uint32_t wb[KT];
#pragma unroll
        for (int w = 0; w < KT; ++w) wb[w] = planesIn[(size_t)w * MTOT + row];

        const float* wr = W + (size_t)o * KREAL;
        float acc = 0.f;
#pragma unroll
        for (int kt = 0; kt < KT; ++kt) {
#pragma unroll
            for (int kk = 0; kk < 32; ++kk) {
                const int k = kt * 32 + kk;
                if (k < KREAL)
                    acc = fmaf((float)((wb[kt] >> kk) & 1u), wr[k], acc);
            }
        }
        const float syn_t = acc + bias[o];

        float u = 0.f, v = 0.f, s = 0.f, mys = 0.f;
#pragma unroll 1
        for (int t = 0; t < 50; ++t) {
            const float sv = __shfl(syn_t, t);
            u = u * 0.5f + sv;
            v = v * 0.75f * (1.0f - s) + u;
            s = (v > 0.5f) ? 1.0f : 0.0f;
            if (lane == t) mys = s;
        }

        if (lane < 50) {
            uint32_t* wp = planesOut + (size_t)(o >> 5) * MTOT + row;
            const uint32_t bit = 1u << (o & 31);
            const bool prov = (*wp & bit) != 0u;
            const bool ex = (mys > 0.5f);
            if (prov != ex) atomicXor(wp, bit);
        }
    }
}

// ------------------------- fc4 GEMM (N=2, K=128, exact) ---------------------
__global__ __launch_bounds__(256) void fc4_gemm_kernel(
    const uint32_t* __restrict__ P3,          // planes [4][MTOT]
    const float* __restrict__ W, const float* __restrict__ bias,
    float* __restrict__ syn4)
{
    const int m = blockIdx.x * 256 + threadIdx.x;
    const unsigned long long w0 =
        (unsigned long long)P3[m] | ((unsigned long long)P3[(size_t)MTOT + m] << 32);
    const unsigned long long w1 =
        (unsigned long long)P3[2 * (size_t)MTOT + m] |
        ((unsigned long long)P3[3 * (size_t)MTOT + m] << 32);
    float a0 = 0.f, a1 = 0.f;
#pragma unroll
    for (int i = 0; i < 64; ++i) {
        const float bit = ((w0 >> i) & 1ULL) ? 1.f : 0.f;
        a0 = fmaf(bit, W[i], a0);
        a1 = fmaf(bit, W[128 + i], a1);
    }
#pragma unroll
    for (int i = 0; i < 64; ++i) {
        const float bit = ((w1 >> i) & 1ULL) ? 1.f : 0.f;
        a0 = fmaf(bit, W[64 + i], a0);
        a1 = fmaf(bit, W[192 + i], a1);
    }
    syn4[(size_t)m * 2]     = a0 + bias[0];
    syn4[(size_t)m * 2 + 1] = a1 + bias[1];
}

__global__ __launch_bounds__(64) void fc4_scan_kernel(
    const float* __restrict__ syn4, float* __restrict__ out)
{
    const int b = blockIdx.x * 64 + threadIdx.x;
    float u0 = 0.f, v0 = 0.f, s0 = 0.f, acc0 = 0.f;
    float u1 = 0.f, v1 = 0.f, s1 = 0.f, acc1 = 0.f;
    for (int t = 0; t < 50; ++t) {
        const float x0 = syn4[((size_t)b * 50 + t) * 2];
        const float x1 = syn4[((size_t)b * 50 + t) * 2 + 1];
        neuron_update(x0, u0, v0, s0); acc0 += s0;
        neuron_update(x1, u1, v1, s1); acc1 += s1;
    }
    out[b * 2]     = acc0 / 50.0f;
    out[b * 2 + 1] = acc1 / 50.0f;
}

// ---------------------------------------------------------------------------
extern "C" void kernel_launch(void* const* d_in, const int* in_sizes, int n_in,
                              void* d_out, int out_size, void* d_ws, size_t ws_size,
                              hipStream_t stream) {
    (void)in_sizes; (void)n_in; (void)out_size;
    const float* normal = (const float*)d_in[0];
    const float* xscan  = (const float*)d_in[1];
    const float* w1  = (const float*)d_in[3];
    const float* b1  = (const float*)d_in[4];
    const float* w2  = (const float*)d_in[5];
    const float* b2  = (const float*)d_in[6];
    const float* w3  = (const float*)d_in[7];
    const float* b3  = (const float*)d_in[8];
    const float* fw1 = (const float*)d_in[9];
    const float* fb1 = (const float*)d_in[10];
    const float* fw2 = (const float*)d_in[11];
    const float* fb2 = (const float*)d_in[12];
    const float* fw3 = (const float*)d_in[13];
    const float* fb3 = (const float*)d_in[14];
    const float* fw4 = (const float*)d_in[15];
    const float* fb4 = (const float*)d_in[16];
    float* out = (float*)d_out;

    char* wp = (char*)d_ws;
    size_t off = 0;
    auto take = [&](size_t bytes) -> void* {
        void* p = wp + off;
        off += (bytes + 255) & ~(size_t)255;
        return p;
    };
    unsigned short* Wg1 = (unsigned short*)take((size_t)2 * 12 * 8192 * 2);
    unsigned short* Wg2 = (unsigned short*)take((size_t)2 * 12 * 8192 * 2);
    unsigned short* Wg3 = (unsigned short*)take((size_t)1 * 12 * 8192 * 2);
    unsigned long long* S1  = (unsigned long long*)take((size_t)NB * 50 * 15 * 8);
    unsigned int*       S2  = (unsigned int*)take((size_t)NB * 50 * 15 * 4);
    uint32_t* ST0 = (uint32_t*)take((size_t)8 * MTOT * 4);
    uint32_t* ST1 = (uint32_t*)take((size_t)8 * MTOT * 4);
    uint32_t* ST2 = (uint32_t*)take((size_t)8 * MTOT * 4);
    uint32_t* ST3 = (uint32_t*)take((size_t)4 * MTOT * 4);
    float*    syn4 = (float*)take((size_t)MTOT * 2 * 4);
    unsigned int* cnts = (unsigned int*)take(256);
    uint32_t* list0 = (uint32_t*)take((size_t)NB * 256 * 4);
    uint32_t* list1 = (uint32_t*)take((size_t)NB * 256 * 4);
    uint32_t* list2 = (uint32_t*)take((size_t)NB * 128 * 4);

    int chunk = NB;
    while (chunk > 128 && off + (size_t)chunk * 50 * 256 * 4 > ws_size) chunk >>= 1;
    float* syn = (float*)take((size_t)chunk * 50 * 256 * 4);

    hipMemsetAsync(cnts, 0, 12, stream);

    pack_w_kernel<<<256, 256, 0, stream>>>(fw1, Wg1, 216);
    pack_w_kernel<<<256, 256, 0, stream>>>(fw2, Wg2, 256);
    pack_w_kernel<<<128, 256, 0, stream>>>(fw3, Wg3, 256);

    conv1_kernel<<<NB, 192, 0, stream>>>(xscan, w1, b1, S1);
    conv2_kernel<<<NB, 128, 0, stream>>>((const unsigned int*)S1, w2, b2, S2);
    conv3_kernel<<<NB / 2, 128, 0, stream>>>(S2, w3, b3, normal, ST0);

    for (int b0 = 0; b0 < NB; b0 += chunk) {
        mfma_fc_kernel<<<dim3(chunk * 50 / 128, 2), 256, 0, stream>>>(
            ST0, Wg1, fb1, syn, 256, b0 * 50);
        fc_scan_flag_kernel<256><<<chunk, 256, 0, stream>>>(syn, ST1, b0, list0, cnts + 0);
        repair_kernel<7, 216><<<512, 256, 0, stream>>>(ST0, fw1, fb1, ST1, list0, cnts + 0);

        mfma_fc_kernel<<<dim3(chunk * 50 / 128, 2), 256, 0, stream>>>(
            ST1, Wg2, fb2, syn, 256, b0 * 50);
        fc_scan_flag_kernel<256><<<chunk, 256, 0, stream>>>(syn, ST2, b0, list1, cnts + 1);
        repair_kernel<8, 256><<<512, 256, 0, stream>>>(ST1, fw2, fb2, ST2, list1, cnts + 1);

        mfma_fc_kernel<<<dim3(chunk * 50 / 128, 1), 256, 0, stream>>>(
            ST2, Wg3, fb3, syn, 128, b0 * 50);
        fc_scan_flag_kernel<128><<<chunk, 128, 0, stream>>>(syn, ST3, b0, list2, cnts + 2);
        repair_kernel<8, 256><<<512, 256, 0, stream>>>(ST2, fw3, fb3, ST3, list2, cnts + 2);
    }

    fc4_gemm_kernel<<<MTOT / 256, 256, 0, stream>>>(ST3, fw4, fb4, syn4);
    fc4_scan_kernel<<<NB / 64, 64, 0, stream>>>(syn4, out);
}

// Round 12
// 1585.982 us; speedup vs baseline: 1.1440x; 1.0273x over previous
//
#include <hip/hip_runtime.h>
#include <cstdint>
#include <cstddef>

// ---------------------------------------------------------------------------
// ActorNetSpiking: layer-by-layer over time; spikes bit-packed in transposed
// u32 planes. FC layers: bf16x3-split MFMA GEMM (fast, provisional) + LIF
// scan (register-prefetched syn: 50 independent loads -> BW-bound, not
// latency-bound) that FLAGS neurons with any |v-0.5| < DELTA + exact-repair
// kernel (ascending-k single-accumulator f32 fmaf chain, validated reference
// order). Convs: register-PINNED weights (asm "+v").
// ---------------------------------------------------------------------------

#define NB 4096
#define MTOT (NB * 50)
#define DELTA 1e-3f

typedef __attribute__((ext_vector_type(8))) short bf16x8;
typedef __attribute__((ext_vector_type(4))) float f32x4;
typedef __attribute__((ext_vector_type(4))) uint32_t u32x4;

__device__ __forceinline__ void neuron_update(float syn, float& u, float& v, float& s) {
    u = u * 0.5f + syn;
    v = v * 0.75f * (1.0f - s) + u;
    s = (v > 0.5f) ? 1.0f : 0.0f;
}

// ------------------------- conv1: (B,1,360) -> (B,5,178) --------------------
__global__ __launch_bounds__(192) void conv1_kernel(
    const float* __restrict__ x, const float* __restrict__ w1,
    const float* __restrict__ b1, unsigned long long* __restrict__ S1)
{
    __shared__ float xl[9000];
    const int tid = threadIdx.x;
    const int b = blockIdx.x;
    const int j = tid;
    const int lbase = (j < 178) ? 2 * j : 354;

    float wr[25], br[5];
#pragma unroll
    for (int q = 0; q < 25; ++q) wr[q] = w1[q];
#pragma unroll
    for (int o = 0; o < 5; ++o) br[o] = b1[o];
#pragma unroll
    for (int q = 0; q < 25; ++q) asm volatile("" : "+v"(wr[q]));
#pragma unroll
    for (int o = 0; o < 5; ++o) asm volatile("" : "+v"(br[o]));

    float u[5], v[5], s[5];
#pragma unroll
    for (int o = 0; o < 5; ++o) { u[o] = 0.f; v[o] = 0.f; s[o] = 0.f; }

    const float* xb = x + (size_t)b * 18000;
    for (int half = 0; half < 2; ++half) {
        const int t0 = half * 25;
        __syncthreads();
        for (int e = tid; e < 9000; e += 192)
            xl[e] = xb[(e / 25) * 50 + t0 + (e % 25)];
        __syncthreads();
        for (int dt = 0; dt < 25; ++dt) {
            const int t = t0 + dt;
            float acc[5];
#pragma unroll
            for (int o = 0; o < 5; ++o) acc[o] = 0.f;
#pragma unroll
            for (int k = 0; k < 5; ++k) {
                const float xk = xl[(lbase + k) * 25 + dt];
#pragma unroll
                for (int o = 0; o < 5; ++o)
                    acc[o] = fmaf(wr[o * 5 + k], xk, acc[o]);
            }
#pragma unroll
            for (int o = 0; o < 5; ++o) {
                const float syn = acc[o] + br[o];
                neuron_update(syn, u[o], v[o], s[o]);
                unsigned long long m = __ballot(j < 178 && s[o] > 0.5f);
                if ((tid & 63) == 0)
                    S1[(((size_t)b * 50 + t) * 5 + o) * 3 + (tid >> 6)] = m;
            }
        }
    }
}

// ------------------------- conv2: (B,5,178) -> (B,5,87) ---------------------
__global__ __launch_bounds__(128) void conv2_kernel(
    const unsigned int* __restrict__ S1, const float* __restrict__ w2,
    const float* __restrict__ b2, unsigned int* __restrict__ S2)
{
    __shared__ unsigned int s1l[1501];
    const int tid = threadIdx.x;
    const int b = blockIdx.x;

    float wr[125], br[5];
#pragma unroll
    for (int q = 0; q < 125; ++q) wr[q] = w2[q];
#pragma unroll
    for (int o = 0; o < 5; ++o) br[o] = b2[o];
#pragma unroll
    for (int q = 0; q < 125; ++q) asm volatile("" : "+v"(wr[q]));
#pragma unroll
    for (int o = 0; o < 5; ++o) asm volatile("" : "+v"(br[o]));

    const unsigned int* src = S1 + (size_t)b * 1500;
    for (int e = tid; e < 1500; e += 128) s1l[e] = src[e];
    __syncthreads();

    const int p = (tid < 87) ? 2 * tid : 172;
    const int pw = p >> 5, ps = p & 31;

    float u[5], v[5], s[5];
#pragma unroll
    for (int o = 0; o < 5; ++o) { u[o] = 0.f; v[o] = 0.f; s[o] = 0.f; }

    for (int t = 0; t < 50; ++t) {
        float acc[5];
#pragma unroll
        for (int o = 0; o < 5; ++o) acc[o] = 0.f;
#pragma unroll
        for (int ci = 0; ci < 5; ++ci) {
            const int base = (t * 5 + ci) * 6 + pw;
            const unsigned int w5 = (unsigned int)(
                ((((unsigned long long)s1l[base + 1]) << 32) |
                 (unsigned long long)s1l[base]) >> ps);
#pragma unroll
            for (int k = 0; k < 5; ++k) {
                const float xk = (float)((w5 >> k) & 1u);
#pragma unroll
                for (int o = 0; o < 5; ++o)
                    acc[o] = fmaf(wr[o * 25 + ci * 5 + k], xk, acc[o]);
            }
        }
#pragma unroll
        for (int o = 0; o < 5; ++o) {
            const float syn = acc[o] + br[o];
            neuron_update(syn, u[o], v[o], s[o]);
            unsigned long long m = __ballot(tid < 87 && s[o] > 0.5f);
            const size_t outb = (((size_t)b * 50 + t) * 5 + o) * 3;
            if (tid == 0) {
                S2[outb]     = (unsigned int)m;
                S2[outb + 1] = (unsigned int)(m >> 32);
            }
            if (tid == 64) S2[outb + 2] = (unsigned int)m;
        }
    }
}

// ------------------------- conv3: (B,5,87) -> transposed 216-bit rows -------
__global__ __launch_bounds__(128) void conv3_kernel(
    const unsigned int* __restrict__ S2, const float* __restrict__ w3,
    const float* __restrict__ b3, const float* __restrict__ normal,
    unsigned int* __restrict__ ST0)
{
    __shared__ unsigned int s2l[2][751];
    const int tid = threadIdx.x;
    const int wv = tid >> 6;
    const int lane = tid & 63;
    const int b = blockIdx.x * 2 + wv;

    float wr[125], br[5];
#pragma unroll
    for (int q = 0; q < 125; ++q) wr[q] = w3[q];
#pragma unroll
    for (int o = 0; o < 5; ++o) br[o] = b3[o];
#pragma unroll
    for (int q = 0; q < 125; ++q) asm volatile("" : "+v"(wr[q]));
#pragma unroll
    for (int o = 0; o < 5; ++o) asm volatile("" : "+v"(br[o]));

    unsigned int* sl = s2l[wv];
    const unsigned int* src = S2 + (size_t)b * 750;
    for (int e = lane; e < 750; e += 64) sl[e] = src[e];
    __syncthreads();

    const int p = (lane < 42) ? 2 * lane : 82;
    const int pw = p >> 5, ps = p & 31;

    float u[5], v[5], s[5];
#pragma unroll
    for (int o = 0; o < 5; ++o) { u[o] = 0.f; v[o] = 0.f; s[o] = 0.f; }

    for (int t = 0; t < 50; ++t) {
        float acc[5];
#pragma unroll
        for (int o = 0; o < 5; ++o) acc[o] = 0.f;
#pragma unroll
        for (int ci = 0; ci < 5; ++ci) {
            const int base = (t * 5 + ci) * 3 + pw;
            const unsigned int w5 = (unsigned int)(
                ((((unsigned long long)sl[base + 1]) << 32) |
                 (unsigned long long)sl[base]) >> ps);
#pragma unroll
            for (int k = 0; k < 5; ++k) {
                const float xk = (float)((w5 >> k) & 1u);
#pragma unroll
                for (int o = 0; o < 5; ++o)
                    acc[o] = fmaf(wr[o * 25 + ci * 5 + k], xk, acc[o]);
            }
        }
        unsigned long long m[5];
#pragma unroll
        for (int o = 0; o < 5; ++o) {
            const float syn = acc[o] + br[o];
            neuron_update(syn, u[o], v[o], s[o]);
            m[o] = __ballot(lane < 42 && s[o] > 0.5f);
        }
        const unsigned long long nm =
            __ballot(lane < 6 && normal[((size_t)b * 6 + lane) * 50 + t] > 0.5f);
        if (lane == 0) {
            const unsigned long long r0 = m[0] | (m[1] << 42);
            const unsigned long long r1 = (m[1] >> 22) | (m[2] << 20) | (m[3] << 62);
            const unsigned long long r2 = (m[3] >> 2) | (m[4] << 40);
            const unsigned long long r3 = (m[4] >> 24) | (nm << 18);
            const size_t mrow = (size_t)b * 50 + t;
            ST0[0 * (size_t)MTOT + mrow] = (unsigned int)r0;
            ST0[1 * (size_t)MTOT + mrow] = (unsigned int)(r0 >> 32);
            ST0[2 * (size_t)MTOT + mrow] = (unsigned int)r1;
            ST0[3 * (size_t)MTOT + mrow] = (unsigned int)(r1 >> 32);
            ST0[4 * (size_t)MTOT + mrow] = (unsigned int)r2;
            ST0[5 * (size_t)MTOT + mrow] = (unsigned int)(r2 >> 32);
            ST0[6 * (size_t)MTOT + mrow] = (unsigned int)r3;
            ST0[7 * (size_t)MTOT + mrow] = 0u;
        }
    }
}

// ------------------------- weight split+swizzle prep (validated r2) ---------
__global__ __launch_bounds__(256) void pack_w_kernel(
    const float* __restrict__ W, unsigned short* __restrict__ dst, int KREAL)
{
    const int idx = blockIdx.x * 256 + threadIdx.x;
    const int n = idx >> 8, k = idx & 255;
    const float w = (k < KREAL) ? W[(size_t)n * KREAL + k] : 0.f;
    const uint32_t u0 = __float_as_uint(w);
    const unsigned short h0 = (unsigned short)(u0 >> 16);
    const float p0 = __uint_as_float(u0 & 0xFFFF0000u);
    const float r1 = w - p0;
    const uint32_t u1 = __float_as_uint(r1);
    const unsigned short h1 = (unsigned short)(u1 >> 16);
    const float p1 = __uint_as_float(u1 & 0xFFFF0000u);
    const float r2 = r1 - p1;
    const unsigned short h2 = (unsigned short)(__float_as_uint(r2) >> 16);

    const int nb = n >> 7, row = n & 127;
    const int kc = k >> 6, kl = k & 63;
    const int kbyte = (kl * 2) ^ ((row & 7) << 4);
    const size_t base = ((size_t)nb * 12 + (size_t)kc * 3) * 8192 + row * 64 + (kbyte >> 1);
    dst[base] = h0;
    dst[base + 8192] = h1;
    dst[base + 16384] = h2;
}

// ------------------------- MFMA FC GEMM (validated r2/r9 structure) ---------
__global__ __launch_bounds__(256, 3) void mfma_fc_kernel(
    const uint32_t* __restrict__ bitsT,       // planes [8][MTOT]
    const unsigned short* __restrict__ wg,    // pre-swizzled tiles
    const float* __restrict__ bias,
    float* __restrict__ syn,                  // [Mchunk][Ntot]
    int Ntot, int row0)
{
    __shared__ __align__(16) unsigned short blds[3][8192];  // 3 x 16KB
    __shared__ __align__(16) uint32_t bits_lds[1024];       // [plane w][128 m]

    const int tid = threadIdx.x;
    const int lane = tid & 63;
    const int wid = tid >> 6;
    const int wm = wid >> 1, wn = wid & 1;
    const int m0 = blockIdx.x * 128;
    const int nb = blockIdx.y;
    const int nbase = nb * 128;

    {
        const uint32_t* g = bitsT + (size_t)(tid >> 5) * MTOT + (row0 + m0) + (tid & 31) * 4;
        uint32_t* l = bits_lds + wid * 256;
        __builtin_amdgcn_global_load_lds(
            (const __attribute__((address_space(1))) uint32_t*)g,
            (__attribute__((address_space(3))) uint32_t*)l, 16, 0, 0);
    }

    auto stage = [&](int t_idx, int buf) {
        const unsigned short* wt = wg + ((size_t)(nb * 12 + t_idx)) * 8192;
#pragma unroll
        for (int j = 0; j < 4; ++j) {
            const char* g = (const char*)wt + j * 4096 + wid * 1024 + lane * 16;
            char* l = (char*)&blds[buf][0] + j * 4096 + wid * 1024;
            __builtin_amdgcn_global_load_lds(
                (const __attribute__((address_space(1))) uint32_t*)g,
                (__attribute__((address_space(3))) uint32_t*)l, 16, 0, 0);
        }
    };

    stage(0, 0);
    stage(1, 1);

    f32x4 acc[4][4];
#pragma unroll
    for (int i = 0; i < 4; ++i)
#pragma unroll
        for (int j = 0; j < 4; ++j) acc[i][j] = (f32x4){0.f, 0.f, 0.f, 0.f};

    union frag { u32x4 u; bf16x8 h; };
    frag afr[4][2];

#pragma unroll
    for (int s = 0; s < 12; ++s) {
        if (s < 11) asm volatile("s_waitcnt vmcnt(4)\ns_barrier" ::: "memory");
        else        asm volatile("s_waitcnt vmcnt(0)\ns_barrier" ::: "memory");
        if (s + 2 < 12) stage(s + 2, (s + 2) % 3);

        const int kc = s / 3;
        if ((s % 3) == 0) {
#pragma unroll
            for (int mi = 0; mi < 4; ++mi) {
                const int row = wm * 64 + mi * 16 + (lane & 15);
#pragma unroll
                for (int kk = 0; kk < 2; ++kk) {
                    const uint32_t wbits = bits_lds[(kc * 2 + kk) * 128 + row];
                    const uint32_t bb = (wbits >> ((lane >> 4) * 8)) & 0xFFu;
                    u32x4 e;
#pragma unroll
                    for (int j = 0; j < 4; ++j) {
                        uint32_t r = ((bb >> (2 * j)) & 1u) ? 0x3F80u : 0u;
                        if ((bb >> (2 * j + 1)) & 1u) r |= 0x3F800000u;
                        e[j] = r;
                    }
                    afr[mi][kk].u = e;
                }
            }
        }

        const char* bt = (const char*)&blds[s % 3][0];
        __builtin_amdgcn_s_setprio(1);
#pragma unroll
        for (int kk = 0; kk < 2; ++kk) {
#pragma unroll
            for (int ni = 0; ni < 4; ++ni) {
                const int r = wn * 64 + ni * 16 + (lane & 15);
                const int kb = kk * 64 + (lane >> 4) * 16;
                const int off = r * 128 + (kb ^ ((r & 7) << 4));
                bf16x8 bfr = *reinterpret_cast<const bf16x8*>(bt + off);
#pragma unroll
                for (int mi = 0; mi < 4; ++mi)
                    acc[mi][ni] = __builtin_amdgcn_mfma_f32_16x16x32_bf16(
                        afr[mi][kk].h, bfr, acc[mi][ni], 0, 0, 0);
            }
        }
        __builtin_amdgcn_s_setprio(0);
    }

#pragma unroll
    for (int ni = 0; ni < 4; ++ni) {
        const int n = nbase + wn * 64 + ni * 16 + (lane & 15);
        const float bs = bias[n];
#pragma unroll
        for (int mi = 0; mi < 4; ++mi) {
            const int mr = m0 + wm * 64 + mi * 16 + ((lane >> 4) << 2);
            float* dst = syn + (size_t)mr * Ntot + n;
            f32x4 a = acc[mi][ni];
#pragma unroll
            for (int rr = 0; rr < 4; ++rr) dst[(size_t)rr * Ntot] = a[rr] + bs;
        }
    }
}

// ------------------------- FC scan + flag: LIF -> planes + repair list ------
// syn prefetched into registers (50 independent loads) -> BW-bound.
template <int N>
__global__ __launch_bounds__(N) void fc_scan_flag_kernel(
    const float* __restrict__ syn,        // [chunk*50][N]
    uint32_t* __restrict__ SFT,           // planes [N/32][MTOT]
    int b0,
    uint32_t* __restrict__ list, unsigned int* __restrict__ cnt)
{
    const int tid = threadIdx.x;
    const int lane = tid & 63;
    const int ob = tid >> 6;
    const int bl = blockIdx.x;
    const int o = tid;

    float sv[50];
#pragma unroll
    for (int t = 0; t < 50; ++t)
        sv[t] = syn[((size_t)bl * 50 + t) * N + o];

    float u = 0.f, v = 0.f, s = 0.f;
    bool flag = false;
#pragma unroll
    for (int t = 0; t < 50; ++t) {
        u = u * 0.5f + sv[t];
        v = v * 0.75f * (1.0f - s) + u;
        flag |= (fabsf(v - 0.5f) < DELTA);
        s = (v > 0.5f) ? 1.0f : 0.0f;
        const unsigned long long m = __ballot(s > 0.5f);
        if (lane == 0) {
            const size_t row = (size_t)(b0 + bl) * 50 + t;
            SFT[(size_t)(2 * ob) * MTOT + row]     = (uint32_t)m;
            SFT[(size_t)(2 * ob + 1) * MTOT + row] = (uint32_t)(m >> 32);
        }
    }
    const unsigned long long fm = __ballot(flag);
    unsigned int base = 0;
    if (lane == 0 && fm) base = atomicAdd(cnt, (unsigned int)__popcll(fm));
    base = __shfl(base, 0);
    if (flag) {
        const unsigned int off = (unsigned int)__popcll(fm & ((1ULL << lane) - 1ULL));
        list[base + off] = ((unsigned int)(b0 + bl) << 8) | (unsigned int)o;
    }
}

// ------------------------- exact repair: flagged neurons --------------------
template <int KT, int KREAL>
__global__ __launch_bounds__(256) void repair_kernel(
    const uint32_t* __restrict__ planesIn,   // [KT..8][MTOT]
    const float* __restrict__ W,             // (NOUT, KREAL) row-major
    const float* __restrict__ bias,
    uint32_t* __restrict__ planesOut,        // [NOUT/32][MTOT]
    const uint32_t* __restrict__ list,
    const unsigned int* __restrict__ cnt)
{
    const int lane = threadIdx.x & 63;
    const int wid = blockIdx.x * 4 + (threadIdx.x >> 6);
    const int nwaves = gridDim.x * 4;
    const unsigned int n = *cnt;

    for (unsigned int idx = wid; idx < n; idx += nwaves) {
        const uint32_t e = list[idx];
        const int b = __builtin_amdgcn_readfirstlane((int)(e >> 8));
        const int o = __builtin_amdgcn_readfirstlane((int)(e & 255u));
        const int tl = (lane < 50) ? lane : 49;
        const size_t row = (size_t)b * 50 + tl;

        uint32_t wb[KT];
#pragma unroll
        for (int w = 0; w < KT; ++w) wb[w] = planesIn[(size_t)w * MTOT + row];

        const float* wr = W + (size_t)o * KREAL;
        float acc = 0.f;
#pragma unroll
        for (int kt = 0; kt < KT; ++kt) {
#pragma unroll
            for (int kk = 0; kk < 32; ++kk) {
                const int k = kt * 32 + kk;
                if (k < KREAL)
                    acc = fmaf((float)((wb[kt] >> kk) & 1u), wr[k], acc);
            }
        }
        const float syn_t = acc + bias[o];

        float u = 0.f, v = 0.f, s = 0.f, mys = 0.f;
#pragma unroll 1
        for (int t = 0; t < 50; ++t) {
            const float sv = __shfl(syn_t, t);
            u = u * 0.5f + sv;
            v = v * 0.75f * (1.0f - s) + u;
            s = (v > 0.5f) ? 1.0f : 0.0f;
            if (lane == t) mys = s;
        }

        if (lane < 50) {
            uint32_t* wp = planesOut + (size_t)(o >> 5) * MTOT + row;
            const uint32_t bit = 1u << (o & 31);
            const bool prov = (*wp & bit) != 0u;
            const bool ex = (mys > 0.5f);
            if (prov != ex) atomicXor(wp, bit);
        }
    }
}

// ------------------------- fc4 GEMM (N=2, K=128, exact) ---------------------
__global__ __launch_bounds__(256) void fc4_gemm_kernel(
    const uint32_t* __restrict__ P3,          // planes [4][MTOT]
    const float* __restrict__ W, const float* __restrict__ bias,
    float* __restrict__ syn4)
{
    const int m = blockIdx.x * 256 + threadIdx.x;
    const unsigned long long w0 =
        (unsigned long long)P3[m] | ((unsigned long long)P3[(size_t)MTOT + m] << 32);
    const unsigned long long w1 =
        (unsigned long long)P3[2 * (size_t)MTOT + m] |
        ((unsigned long long)P3[3 * (size_t)MTOT + m] << 32);
    float a0 = 0.f, a1 = 0.f;
#pragma unroll
    for (int i = 0; i < 64; ++i) {
        const float bit = ((w0 >> i) & 1ULL) ? 1.f : 0.f;
        a0 = fmaf(bit, W[i], a0);
        a1 = fmaf(bit, W[128 + i], a1);
    }
#pragma unroll
    for (int i = 0; i < 64; ++i) {
        const float bit = ((w1 >> i) & 1ULL) ? 1.f : 0.f;
        a0 = fmaf(bit, W[64 + i], a0);
        a1 = fmaf(bit, W[192 + i], a1);
    }
    syn4[(size_t)m * 2]     = a0 + bias[0];
    syn4[(size_t)m * 2 + 1] = a1 + bias[1];
}

__global__ __launch_bounds__(64) void fc4_scan_kernel(
    const float* __restrict__ syn4, float* __restrict__ out)
{
    const int b = blockIdx.x * 64 + threadIdx.x;
    float u0 = 0.f, v0 = 0.f, s0 = 0.f, acc0 = 0.f;
    float u1 = 0.f, v1 = 0.f, s1 = 0.f, acc1 = 0.f;
    for (int t = 0; t < 50; ++t) {
        const float x0 = syn4[((size_t)b * 50 + t) * 2];
        const float x1 = syn4[((size_t)b * 50 + t) * 2 + 1];
        neuron_update(x0, u0, v0, s0); acc0 += s0;
        neuron_update(x1, u1, v1, s1); acc1 += s1;
    }
    out[b * 2]     = acc0 / 50.0f;
    out[b * 2 + 1] = acc1 / 50.0f;
}

// ---------------------------------------------------------------------------
extern "C" void kernel_launch(void* const* d_in, const int* in_sizes, int n_in,
                              void* d_out, int out_size, void* d_ws, size_t ws_size,
                              hipStream_t stream) {
    (void)in_sizes; (void)n_in; (void)out_size;
    const float* normal = (const float*)d_in[0];
    const float* xscan  = (const float*)d_in[1];
    const float* w1  = (const float*)d_in[3];
    const float* b1  = (const float*)d_in[4];
    const float* w2  = (const float*)d_in[5];
    const float* b2  = (const float*)d_in[6];
    const float* w3  = (const float*)d_in[7];
    const float* b3  = (const float*)d_in[8];
    const float* fw1 = (const float*)d_in[9];
    const float* fb1 = (const float*)d_in[10];
    const float* fw2 = (const float*)d_in[11];
    const float* fb2 = (const float*)d_in[12];
    const float* fw3 = (const float*)d_in[13];
    const float* fb3 = (const float*)d_in[14];
    const float* fw4 = (const float*)d_in[15];
    const float* fb4 = (const float*)d_in[16];
    float* out = (float*)d_out;

    char* wp = (char*)d_ws;
    size_t off = 0;
    auto take = [&](size_t bytes) -> void* {
        void* p = wp + off;
        off += (bytes + 255) & ~(size_t)255;
        return p;
    };
    unsigned short* Wg1 = (unsigned short*)take((size_t)2 * 12 * 8192 * 2);
    unsigned short* Wg2 = (unsigned short*)take((size_t)2 * 12 * 8192 * 2);
    unsigned short* Wg3 = (unsigned short*)take((size_t)1 * 12 * 8192 * 2);
    unsigned long long* S1  = (unsigned long long*)take((size_t)NB * 50 * 15 * 8);
    unsigned int*       S2  = (unsigned int*)take((size_t)NB * 50 * 15 * 4);
    uint32_t* ST0 = (uint32_t*)take((size_t)8 * MTOT * 4);
    uint32_t* ST1 = (uint32_t*)take((size_t)8 * MTOT * 4);
    uint32_t* ST2 = (uint32_t*)take((size_t)8 * MTOT * 4);
    uint32_t* ST3 = (uint32_t*)take((size_t)4 * MTOT * 4);
    float*    syn4 = (float*)take((size_t)MTOT * 2 * 4);
    unsigned int* cnts = (unsigned int*)take(256);
    uint32_t* list0 = (uint32_t*)take((size_t)NB * 256 * 4);
    uint32_t* list1 = (uint32_t*)take((size_t)NB * 256 * 4);
    uint32_t* list2 = (uint32_t*)take((size_t)NB * 128 * 4);

    int chunk = NB;
    while (chunk > 128 && off + (size_t)chunk * 50 * 256 * 4 > ws_size) chunk >>= 1;
    float* syn = (float*)take((size_t)chunk * 50 * 256 * 4);

    hipMemsetAsync(cnts, 0, 12, stream);

    pack_w_kernel<<<256, 256, 0, stream>>>(fw1, Wg1, 216);
    pack_w_kernel<<<256, 256, 0, stream>>>(fw2, Wg2, 256);
    pack_w_kernel<<<128, 256, 0, stream>>>(fw3, Wg3, 256);

    conv1_kernel<<<NB, 192, 0, stream>>>(xscan, w1, b1, S1);
    conv2_kernel<<<NB, 128, 0, stream>>>((const unsigned int*)S1, w2, b2, S2);
    conv3_kernel<<<NB / 2, 128, 0, stream>>>(S2, w3, b3, normal, ST0);

    for (int b0 = 0; b0 < NB; b0 += chunk) {
        mfma_fc_kernel<<<dim3(chunk * 50 / 128, 2), 256, 0, stream>>>(
            ST0, Wg1, fb1, syn, 256, b0 * 50);
        fc_scan_flag_kernel<256><<<chunk, 256, 0, stream>>>(syn, ST1, b0, list0, cnts + 0);
        repair_kernel<7, 216><<<512, 256, 0, stream>>>(ST0, fw1, fb1, ST1, list0, cnts + 0);

        mfma_fc_kernel<<<dim3(chunk * 50 / 128, 2), 256, 0, stream>>>(
            ST1, Wg2, fb2, syn, 256, b0 * 50);
        fc_scan_flag_kernel<256><<<chunk, 256, 0, stream>>>(syn, ST2, b0, list1, cnts + 1);
        repair_kernel<8, 256><<<512, 256, 0, stream>>>(ST1, fw2, fb2, ST2, list1, cnts + 1);

        mfma_fc_kernel<<<dim3(chunk * 50 / 128, 1), 256, 0, stream>>>(
            ST2, Wg3, fb3, syn, 128, b0 * 50);
        fc_scan_flag_kernel<128><<<chunk, 128, 0, stream>>>(syn, ST3, b0, list2, cnts + 2);
        repair_kernel<8, 256><<<512, 256, 0, stream>>>(ST2, fw3, fb3, ST3, list2, cnts + 2);
    }

    fc4_gemm_kernel<<<MTOT / 256, 256, 0, stream>>>(ST3, fw4, fb4, syn4);
    fc4_scan_kernel<<<NB / 64, 64, 0, stream>>>(syn4, out);
}